// Round 13
// baseline (608.537 us; speedup 1.0000x reference)
//
#include <hip/hip_runtime.h>
#include <stdint.h>

// Qwen2 attention layer, bf16-MFMA pipeline.
// B=2 S=2048 HID=3584 NH=28 NKV=4 D=128 (GQA rep=7)

typedef unsigned short u16;
typedef __bf16 bf16x8 __attribute__((ext_vector_type(8)));
typedef float f32x4 __attribute__((ext_vector_type(4)));

#define B_      2
#define S_      2048
#define HID_    3584
#define NH_     28
#define NKV_    4
#define HD_     128
#define NREP_   7
#define QKVW_   4608   // 3584 q + 512 k + 512 v
#define M_      4096   // B*S
#define SCALING_ 0.08838834764831843f

__device__ __forceinline__ u16 f2bf(float f) {
  union { float f; unsigned u; } x; x.f = f;
  return (u16)((x.u + 0x7FFFu + ((x.u >> 16) & 1u)) >> 16);
}
__device__ __forceinline__ float bf2f(u16 h) {
  union { unsigned u; float f; } x; x.u = ((unsigned)h) << 16;
  return x.f;
}
// pack 2 f32 -> 2 bf16 in one u32 (lo = a, hi = b), RNE
__device__ __forceinline__ unsigned cvtpk_bf16(float a, float b) {
  unsigned r;
  asm("v_cvt_pk_bf16_f32 %0, %1, %2" : "=v"(r) : "v"(a), "v"(b));
  return r;
}

// async global->LDS, 16B/lane; LDS dest is wave-uniform base + lane*16
__device__ __forceinline__ void gl_lds16(const void* g, void* l) {
  __builtin_amdgcn_global_load_lds(
      (__attribute__((address_space(1))) void*)(g),
      (__attribute__((address_space(3))) void*)(l), 16, 0, 0);
}

__device__ __forceinline__ ushort4 cvt4(float4 v) {
  ushort4 o;
  o.x = f2bf(v.x); o.y = f2bf(v.y); o.z = f2bf(v.z); o.w = f2bf(v.w);
  return o;
}

// ---------------- fp32 -> bf16 cast (standalone, fallback path) ----------------
__global__ __launch_bounds__(256) void f2b4_kernel(
    const float4* __restrict__ in, ushort4* __restrict__ out, int n4) {
  int i = blockIdx.x * 256 + threadIdx.x;
  if (i >= n4) return;
  out[i] = cvt4(in[i]);
}

// ---------------- concat q_b|k_b|v_b (standalone, fallback path) ----------------
__global__ __launch_bounds__(256) void bias_cat_kernel(
    const float* __restrict__ qb, const float* __restrict__ kb,
    const float* __restrict__ vb, float* __restrict__ out) {
  int i = blockIdx.x * 256 + threadIdx.x;
  if (i < 3584) out[i] = qb[i];
  else if (i < 4096) out[i] = kb[i - 3584];
  else if (i < 4608) out[i] = vb[i - 4096];
}

// ---------------- megacast: ALL input casts + bias concat (+ optional part-zero) ----------------
__global__ __launch_bounds__(256) void megacast_kernel(
    const float4* __restrict__ hid, const float4* __restrict__ qw,
    const float4* __restrict__ kw, const float4* __restrict__ vw,
    const float4* __restrict__ ow,
    ushort4* __restrict__ hid_b, ushort4* __restrict__ w_b,
    ushort4* __restrict__ ow_b,
    const float* __restrict__ qb, const float* __restrict__ kb,
    const float* __restrict__ vb, float* __restrict__ bias,
    float4* __restrict__ part_zero) {
  const int blk = blockIdx.x;
  const int tid = threadIdx.x;
  if (blk < 14336) {
    int i = blk * 256 + tid;
    hid_b[i] = cvt4(hid[i]);
  } else if (blk < 26880) {
    int i = (blk - 14336) * 256 + tid;
    w_b[i] = cvt4(qw[i]);
  } else if (blk < 28672) {
    int i = (blk - 26880) * 256 + tid;
    w_b[3211264 + i] = cvt4(kw[i]);
  } else if (blk < 30464) {
    int i = (blk - 28672) * 256 + tid;
    w_b[3670016 + i] = cvt4(vw[i]);
  } else if (blk < 43008) {
    int i = (blk - 30464) * 256 + tid;
    ow_b[i] = cvt4(ow[i]);
  } else if (blk < 43026) {
    int i = (blk - 43008) * 256 + tid;
    if (i < 3584) bias[i] = qb[i];
    else if (i < 4096) bias[i] = kb[i - 3584];
    else if (i < 4608) bias[i] = vb[i - 4096];
  } else {
    int i = (blk - 43026) * 256 + tid;  // 1048576 float4 = 4096x1024 f32
    float4 z = {0.f, 0.f, 0.f, 0.f};
    part_zero[i] = z;
  }
}

// ---------------- QKV hybrid GEMM: 256^2 pipelined, Q full-K + KV split-K=4 ----------------
// LPT: LONG Q tiles at blockIdx [0,224) (first block-wave); short KV chunks at
// [224,480) fill the 32 remaining CUs + the post-Q tail.
// kparts==4 -> KV chunks write PLAIN f32 stores into per-chunk buffer (R12:
// 146->130us vs atomics). kparts==1 -> atomicAdd into zeroed single buffer.
__global__ __launch_bounds__(512, 2)
void qkv_hybrid_kernel(const u16* __restrict__ A, const u16* __restrict__ W,
                       const float* __restrict__ bias, u16* __restrict__ qkv,
                       float* __restrict__ kvpart, int kparts) {
  __shared__ u16 sm[65536] __attribute__((aligned(16)));
  const int tid = threadIdx.x;
  const int wave = tid >> 6, lane = tid & 63;
  const int lrow = lane & 15, lquad = lane >> 4;
  const int wm = wave >> 2, wn = wave & 3;
  const int K = HID_;

  const bool isKV = ((int)blockIdx.x >= 224);
  int m0, n0, kb, kc = 0;
  int nt;
  if (isKV) {
    int bid = (int)blockIdx.x - 224;
    int v = (bid & 7) * 32 + (bid >> 3);   // XCD remap over 256
    int tile = v & 63;                     // 16 m x 4 n
    kc = v >> 6;                           // 0..3
    m0 = (tile >> 2) << 8;
    n0 = 3584 + ((tile & 3) << 8);
    kb = kc * 896;
    nt = 14;                               // 896 / 64
  } else {
    int bid = (int)blockIdx.x;
    int v = (bid & 7) * 28 + (bid >> 3);   // XCD remap over 224
    m0 = (v / 14) << 8;
    n0 = (v % 14) << 8;
    kb = 0;
    nt = 56;                               // 3584 / 64
  }

  const int srow = tid >> 3, sg = tid & 7;
  const int aRowBase[4] = {0, 128, 64, 192};   // issue order Aq0, Aq2, Aq1, Aq3
  size_t srcB[4], srcA[4];
  int dstA[4];
#pragma unroll
  for (int o = 0; o < 4; ++o) {
    int rB = o * 64 + srow;
    srcB[o] = (size_t)(n0 + rB) * K + ((sg ^ (rB & 7)) << 3) + kb;
    int rA = aRowBase[o] + srow;
    srcA[o] = (size_t)(m0 + rA) * K + ((sg ^ (rA & 7)) << 3) + kb;
    dstA[o] = aRowBase[o] * 64 + wave * 512;
  }

#pragma unroll
  for (int o = 0; o < 4; ++o)
    gl_lds16(W + srcB[o], sm + 32768 + o * 4096 + wave * 512);
#pragma unroll
  for (int o = 0; o < 4; ++o)
    gl_lds16(A + srcA[o], sm + dstA[o]);

  f32x4 acc[8][4] = {};
  for (int t = 0; t < nt; ++t) {
    const int cur = t & 1, nxt = cur ^ 1;
    const u16* Ab = sm + cur * 16384;
    const u16* Bb = sm + 32768 + cur * 16384;
    u16* An = sm + nxt * 16384;
    u16* Bn = sm + 32768 + nxt * 16384;
    const bool pf = (t + 1 < nt);
    const size_t k1 = (size_t)(t + 1) << 6;

    asm volatile("s_waitcnt vmcnt(2)" ::: "memory");
    __builtin_amdgcn_s_barrier();
    __builtin_amdgcn_sched_barrier(0);

    bf16x8 bfr[4][2], af[4];
    // phase 0
    if (pf) {
      gl_lds16(W + (srcB[0] + k1), Bn + 0 * 4096 + wave * 512);
      gl_lds16(W + (srcB[1] + k1), Bn + 1 * 4096 + wave * 512);
    }
#pragma unroll
    for (int nf = 0; nf < 4; ++nf) {
      int rb = wn * 64 + nf * 16 + lrow;
      bfr[nf][0] = *(const bf16x8*)&Bb[rb * 64 + ((lquad ^ (rb & 7)) << 3)];
    }
#pragma unroll
    for (int j = 0; j < 4; ++j) {
      int ra = wm * 128 + j * 16 + lrow;
      af[j] = *(const bf16x8*)&Ab[ra * 64 + ((lquad ^ (ra & 7)) << 3)];
    }
    __builtin_amdgcn_s_setprio(1);
#pragma unroll
    for (int j = 0; j < 4; ++j)
#pragma unroll
      for (int nf = 0; nf < 4; ++nf)
        acc[j][nf] = __builtin_amdgcn_mfma_f32_16x16x32_bf16(af[j], bfr[nf][0], acc[j][nf], 0, 0, 0);
    __builtin_amdgcn_s_setprio(0);

    // phase 1
    if (pf) {
      gl_lds16(W + (srcB[2] + k1), Bn + 2 * 4096 + wave * 512);
      gl_lds16(W + (srcB[3] + k1), Bn + 3 * 4096 + wave * 512);
    }
#pragma unroll
    for (int nf = 0; nf < 4; ++nf) {
      int rb = wn * 64 + nf * 16 + lrow;
      bfr[nf][1] = *(const bf16x8*)&Bb[rb * 64 + (((4 + lquad) ^ (rb & 7)) << 3)];
    }
#pragma unroll
    for (int j = 0; j < 4; ++j) {
      int ra = wm * 128 + j * 16 + lrow;
      af[j] = *(const bf16x8*)&Ab[ra * 64 + (((4 + lquad) ^ (ra & 7)) << 3)];
    }
    __builtin_amdgcn_s_setprio(1);
#pragma unroll
    for (int j = 0; j < 4; ++j)
#pragma unroll
      for (int nf = 0; nf < 4; ++nf)
        acc[j][nf] = __builtin_amdgcn_mfma_f32_16x16x32_bf16(af[j], bfr[nf][1], acc[j][nf], 0, 0, 0);
    __builtin_amdgcn_s_setprio(0);

    // phase 2 entry
    if (pf) asm volatile("s_waitcnt vmcnt(4)" ::: "memory");
    else    asm volatile("s_waitcnt vmcnt(0)" ::: "memory");
    __builtin_amdgcn_s_barrier();
    __builtin_amdgcn_sched_barrier(0);

    // phase 2
    if (pf) {
      gl_lds16(A + (srcA[0] + k1), An + dstA[0]);
      gl_lds16(A + (srcA[1] + k1), An + dstA[1]);
    }
#pragma unroll
    for (int j = 0; j < 4; ++j) {
      int ra = wm * 128 + 64 + j * 16 + lrow;
      af[j] = *(const bf16x8*)&Ab[ra * 64 + ((lquad ^ (ra & 7)) << 3)];
    }
    __builtin_amdgcn_s_setprio(1);
#pragma unroll
    for (int j = 0; j < 4; ++j)
#pragma unroll
      for (int nf = 0; nf < 4; ++nf)
        acc[4 + j][nf] = __builtin_amdgcn_mfma_f32_16x16x32_bf16(af[j], bfr[nf][0], acc[4 + j][nf], 0, 0, 0);
    __builtin_amdgcn_s_setprio(0);

    // phase 3
    if (pf) {
      gl_lds16(A + (srcA[2] + k1), An + dstA[2]);
      gl_lds16(A + (srcA[3] + k1), An + dstA[3]);
    }
#pragma unroll
    for (int j = 0; j < 4; ++j) {
      int ra = wm * 128 + 64 + j * 16 + lrow;
      af[j] = *(const bf16x8*)&Ab[ra * 64 + (((4 + lquad) ^ (ra & 7)) << 3)];
    }
    __builtin_amdgcn_s_setprio(1);
#pragma unroll
    for (int j = 0; j < 4; ++j)
#pragma unroll
      for (int nf = 0; nf < 4; ++nf)
        acc[4 + j][nf] = __builtin_amdgcn_mfma_f32_16x16x32_bf16(af[j], bfr[nf][1], acc[4 + j][nf], 0, 0, 0);
    __builtin_amdgcn_s_setprio(0);
  }

  // epilogue: C/D layout col=lane&15, row=(lane>>4)*4+reg
  if (isKV) {
    const int cbase = n0 - 3584;
    if (kparts == 4) {
      float* dst = kvpart + (size_t)kc * 4194304;
#pragma unroll
      for (int mf = 0; mf < 8; ++mf) {
        int row = m0 + wm * 128 + mf * 16 + lquad * 4;
#pragma unroll
        for (int nf = 0; nf < 4; ++nf) {
          int col = cbase + wn * 64 + nf * 16 + lrow;
#pragma unroll
          for (int r = 0; r < 4; ++r)
            dst[(size_t)(row + r) * 1024 + col] = acc[mf][nf][r];
        }
      }
    } else {
#pragma unroll
      for (int mf = 0; mf < 8; ++mf) {
        int row = m0 + wm * 128 + mf * 16 + lquad * 4;
#pragma unroll
        for (int nf = 0; nf < 4; ++nf) {
          int col = cbase + wn * 64 + nf * 16 + lrow;
#pragma unroll
          for (int r = 0; r < 4; ++r)
            atomicAdd(&kvpart[(size_t)(row + r) * 1024 + col], acc[mf][nf][r]);
        }
      }
    }
  } else {
#pragma unroll
    for (int mf = 0; mf < 8; ++mf) {
      int row = m0 + wm * 128 + mf * 16 + lquad * 4;
#pragma unroll
      for (int nf = 0; nf < 4; ++nf) {
        int col = n0 + wn * 64 + nf * 16 + lrow;
        float bv = bias[col];
#pragma unroll
        for (int r = 0; r < 4; ++r)
          qkv[(size_t)(row + r) * QKVW_ + col] = f2bf(acc[mf][nf][r] + bv);
      }
    }
  }
}

// ---------------- GEMM-BT 128x128 (fallback QKV) ----------------
__global__ __launch_bounds__(256, 2)
void gemm_bt_kernel(const u16* __restrict__ A, const u16* __restrict__ W,
                    const float* __restrict__ bias,
                    u16* __restrict__ outb, float* __restrict__ outf,
                    int M, int N, int K) {
  __shared__ u16 sm[16384] __attribute__((aligned(16)));  // A 128x64 | B 128x64
  u16* a_sm = sm;
  u16* b_sm = sm + 8192;
  const int tid = threadIdx.x;
  const int wave = tid >> 6, lane = tid & 63;
  const int lrow = lane & 15, lquad = lane >> 4;
  const int nmt = M >> 7, nnt = N >> 7, nwg = nmt * nnt;
  const int chunk = nwg >> 3;
  const int v = ((int)blockIdx.x & 7) * chunk + ((int)blockIdx.x >> 3);
  const int grp = v / (4 * nnt);
  const int rem = v - grp * (4 * nnt);
  const int m0 = (grp * 4 + (rem & 3)) << 7;
  const int n0 = (rem >> 2) << 7;
  const int wr = (wave >> 1) * 64, wc = (wave & 1) * 64;

  const u16* Asrc[4];
  const u16* Bsrc[4];
#pragma unroll
  for (int is = 0; is < 4; ++is) {
    int row = is * 32 + (tid >> 3);
    int col = (((tid & 7) ^ (row & 7)) << 3);
    Asrc[is] = A + (size_t)(m0 + row) * K + col;
    Bsrc[is] = W + (size_t)(n0 + row) * K + col;
  }

  f32x4 acc[4][4] = {};
  for (int k0 = 0; k0 < K; k0 += 64) {
#pragma unroll
    for (int is = 0; is < 4; ++is) {
      gl_lds16(Asrc[is] + k0, a_sm + is * 2048 + wave * 512);
      gl_lds16(Bsrc[is] + k0, b_sm + is * 2048 + wave * 512);
    }
    __syncthreads();
#pragma unroll
    for (int ks = 0; ks < 2; ++ks) {
      bf16x8 af[4], bfr[4];
#pragma unroll
      for (int g4 = 0; g4 < 4; ++g4) {
        int ra = wr + g4 * 16 + lrow;
        af[g4] = *(const bf16x8*)&a_sm[ra * 64 + (((ks * 4 + lquad) ^ (ra & 7)) << 3)];
        int rb = wc + g4 * 16 + lrow;
        bfr[g4] = *(const bf16x8*)&b_sm[rb * 64 + (((ks * 4 + lquad) ^ (rb & 7)) << 3)];
      }
#pragma unroll
      for (int i = 0; i < 4; ++i)
#pragma unroll
        for (int j = 0; j < 4; ++j)
          acc[i][j] = __builtin_amdgcn_mfma_f32_16x16x32_bf16(af[i], bfr[j], acc[i][j], 0, 0, 0);
    }
    __syncthreads();
  }
#pragma unroll
  for (int i = 0; i < 4; ++i) {
    int row = m0 + wr + i * 16 + lquad * 4;
#pragma unroll
    for (int j = 0; j < 4; ++j) {
      int col = n0 + wc + j * 16 + lrow;
      float bv = bias ? bias[col] : 0.f;
#pragma unroll
      for (int r = 0; r < 4; ++r) {
        float v2 = acc[i][j][r] + bv;
        if (outb) outb[(size_t)(row + r) * N + col] = f2bf(v2);
        else      outf[(size_t)(row + r) * N + col] = v2;
      }
    }
  }
}

// ---------------- GEMM-BT 256x256, pipelined (O-proj: 224 blocks, 1 wave) ----------------
__global__ __launch_bounds__(512, 2)
void gemm256_kernel(const u16* __restrict__ A, const u16* __restrict__ W,
                    const float* __restrict__ bias,
                    u16* __restrict__ outb, float* __restrict__ outf,
                    int M, int N, int K) {
  __shared__ u16 sm[65536] __attribute__((aligned(16)));
  const int tid = threadIdx.x;
  const int wave = tid >> 6, lane = tid & 63;
  const int lrow = lane & 15, lquad = lane >> 4;
  const int wm = wave >> 2, wn = wave & 3;
  const int nmt = M >> 8, nnt = N >> 8, nwg = nmt * nnt;
  const int chunk = nwg >> 3;
  const int v = ((int)blockIdx.x & 7) * chunk + ((int)blockIdx.x >> 3);
  const int m0 = (v / nnt) << 8;
  const int n0 = (v % nnt) << 8;

  const int srow = tid >> 3, sg = tid & 7;
  const int aRowBase[4] = {0, 128, 64, 192};
  size_t srcB[4], srcA[4];
  int dstA[4];
#pragma unroll
  for (int o = 0; o < 4; ++o) {
    int rB = o * 64 + srow;
    srcB[o] = (size_t)(n0 + rB) * K + ((sg ^ (rB & 7)) << 3);
    int rA = aRowBase[o] + srow;
    srcA[o] = (size_t)(m0 + rA) * K + ((sg ^ (rA & 7)) << 3);
    dstA[o] = aRowBase[o] * 64 + wave * 512;
  }

#pragma unroll
  for (int o = 0; o < 4; ++o)
    gl_lds16(W + srcB[o], sm + 32768 + o * 4096 + wave * 512);
#pragma unroll
  for (int o = 0; o < 4; ++o)
    gl_lds16(A + srcA[o], sm + dstA[o]);

  f32x4 acc[8][4] = {};
  const int nt = K >> 6;
  for (int t = 0; t < nt; ++t) {
    const int cur = t & 1, nxt = cur ^ 1;
    const u16* Ab = sm + cur * 16384;
    const u16* Bb = sm + 32768 + cur * 16384;
    u16* An = sm + nxt * 16384;
    u16* Bn = sm + 32768 + nxt * 16384;
    const bool pf = (t + 1 < nt);
    const size_t k1 = (size_t)(t + 1) << 6;

    asm volatile("s_waitcnt vmcnt(2)" ::: "memory");
    __builtin_amdgcn_s_barrier();
    __builtin_amdgcn_sched_barrier(0);

    bf16x8 bfr[4][2], af[4];
    // phase 0
    if (pf) {
      gl_lds16(W + (srcB[0] + k1), Bn + 0 * 4096 + wave * 512);
      gl_lds16(W + (srcB[1] + k1), Bn + 1 * 4096 + wave * 512);
    }
#pragma unroll
    for (int nf = 0; nf < 4; ++nf) {
      int rb = wn * 64 + nf * 16 + lrow;
      bfr[nf][0] = *(const bf16x8*)&Bb[rb * 64 + ((lquad ^ (rb & 7)) << 3)];
    }
#pragma unroll
    for (int j = 0; j < 4; ++j) {
      int ra = wm * 128 + j * 16 + lrow;
      af[j] = *(const bf16x8*)&Ab[ra * 64 + ((lquad ^ (ra & 7)) << 3)];
    }
    __builtin_amdgcn_s_setprio(1);
#pragma unroll
    for (int j = 0; j < 4; ++j)
#pragma unroll
      for (int nf = 0; nf < 4; ++nf)
        acc[j][nf] = __builtin_amdgcn_mfma_f32_16x16x32_bf16(af[j], bfr[nf][0], acc[j][nf], 0, 0, 0);
    __builtin_amdgcn_s_setprio(0);

    // phase 1
    if (pf) {
      gl_lds16(W + (srcB[2] + k1), Bn + 2 * 4096 + wave * 512);
      gl_lds16(W + (srcB[3] + k1), Bn + 3 * 4096 + wave * 512);
    }
#pragma unroll
    for (int nf = 0; nf < 4; ++nf) {
      int rb = wn * 64 + nf * 16 + lrow;
      bfr[nf][1] = *(const bf16x8*)&Bb[rb * 64 + (((4 + lquad) ^ (rb & 7)) << 3)];
    }
#pragma unroll
    for (int j = 0; j < 4; ++j) {
      int ra = wm * 128 + j * 16 + lrow;
      af[j] = *(const bf16x8*)&Ab[ra * 64 + (((4 + lquad) ^ (ra & 7)) << 3)];
    }
    __builtin_amdgcn_s_setprio(1);
#pragma unroll
    for (int j = 0; j < 4; ++j)
#pragma unroll
      for (int nf = 0; nf < 4; ++nf)
        acc[j][nf] = __builtin_amdgcn_mfma_f32_16x16x32_bf16(af[j], bfr[nf][1], acc[j][nf], 0, 0, 0);
    __builtin_amdgcn_s_setprio(0);

    // phase 2 entry
    if (pf) asm volatile("s_waitcnt vmcnt(4)" ::: "memory");
    else    asm volatile("s_waitcnt vmcnt(0)" ::: "memory");
    __builtin_amdgcn_s_barrier();
    __builtin_amdgcn_sched_barrier(0);

    // phase 2
    if (pf) {
      gl_lds16(A + (srcA[0] + k1), An + dstA[0]);
      gl_lds16(A + (srcA[1] + k1), An + dstA[1]);
    }
#pragma unroll
    for (int j = 0; j < 4; ++j) {
      int ra = wm * 128 + 64 + j * 16 + lrow;
      af[j] = *(const bf16x8*)&Ab[ra * 64 + ((lquad ^ (ra & 7)) << 3)];
    }
    __builtin_amdgcn_s_setprio(1);
#pragma unroll
    for (int j = 0; j < 4; ++j)
#pragma unroll
      for (int nf = 0; nf < 4; ++nf)
        acc[4 + j][nf] = __builtin_amdgcn_mfma_f32_16x16x32_bf16(af[j], bfr[nf][0], acc[4 + j][nf], 0, 0, 0);
    __builtin_amdgcn_s_setprio(0);

    // phase 3
    if (pf) {
      gl_lds16(A + (srcA[2] + k1), An + dstA[2]);
      gl_lds16(A + (srcA[3] + k1), An + dstA[3]);
    }
#pragma unroll
    for (int j = 0; j < 4; ++j) {
      int ra = wm * 128 + 64 + j * 16 + lrow;
      af[j] = *(const bf16x8*)&Ab[ra * 64 + (((4 + lquad) ^ (ra & 7)) << 3)];
    }
    __builtin_amdgcn_s_setprio(1);
#pragma unroll
    for (int j = 0; j < 4; ++j)
#pragma unroll
      for (int nf = 0; nf < 4; ++nf)
        acc[4 + j][nf] = __builtin_amdgcn_mfma_f32_16x16x32_bf16(af[j], bfr[nf][1], acc[4 + j][nf], 0, 0, 0);
    __builtin_amdgcn_s_setprio(0);
  }

#pragma unroll
  for (int mf = 0; mf < 8; ++mf) {
    int row = m0 + wm * 128 + mf * 16 + lquad * 4;
#pragma unroll
    for (int nf = 0; nf < 4; ++nf) {
      int col = n0 + wn * 64 + nf * 16 + lrow;
      float bv = bias ? bias[col] : 0.f;
#pragma unroll
      for (int r = 0; r < 4; ++r) {
        float val = acc[mf][nf][r] + bv;
        if (outb) outb[(size_t)(row + r) * N + col] = f2bf(val);
        else      outf[(size_t)(row + r) * N + col] = val;
      }
    }
  }
}

// ---------------- finalize: Q-rope + K (sum partials + bias + rope) + vT (sum partials) ----------------
__global__ __launch_bounds__(256) void finalize_kernel(
    u16* __restrict__ qkv, const float* __restrict__ cosb,
    const float* __restrict__ sinb, const float* __restrict__ part,
    const float* __restrict__ bias, u16* __restrict__ vT, int kparts) {
  int t = blockIdx.x * 256 + threadIdx.x;  // 2^22 total
  if (t < (1 << 21)) {
    int d = (t & 15) << 2;        // 0,4,...,60
    int hs = (t >> 4) & 31;
    int s = (t >> 9) & 2047;
    int b = t >> 20;
    size_t base = (size_t)(b * S_ + s) * QKVW_ + hs * HD_;
    float4 c0 = *(const float4*)&cosb[s * HD_ + d];
    float4 s0 = *(const float4*)&sinb[s * HD_ + d];
    float4 c1 = *(const float4*)&cosb[s * HD_ + 64 + d];
    float4 s1 = *(const float4*)&sinb[s * HD_ + 64 + d];
    float x1x, x1y, x1z, x1w, x2x, x2y, x2z, x2w, sc;
    if (hs < NH_) {
      ushort4 x1u = *(const ushort4*)&qkv[base + d];
      ushort4 x2u = *(const ushort4*)&qkv[base + 64 + d];
      sc = SCALING_;
      x1x = bf2f(x1u.x); x1y = bf2f(x1u.y); x1z = bf2f(x1u.z); x1w = bf2f(x1u.w);
      x2x = bf2f(x2u.x); x2y = bf2f(x2u.y); x2z = bf2f(x2u.z); x2w = bf2f(x2u.w);
    } else {
      int pc = (hs - 28) * 128;
      size_t prow = (size_t)(b * S_ + s) * 1024;
      float4 b1 = *(const float4*)&bias[3584 + pc + d];
      float4 b2 = *(const float4*)&bias[3584 + pc + 64 + d];
      x1x = b1.x; x1y = b1.y; x1z = b1.z; x1w = b1.w;
      x2x = b2.x; x2y = b2.y; x2z = b2.z; x2w = b2.w;
      for (int kc = 0; kc < kparts; ++kc) {
        const float* pb = part + (size_t)kc * 4194304;
        float4 p1 = *(const float4*)&pb[prow + pc + d];
        float4 p2 = *(const float4*)&pb[prow + pc + 64 + d];
        x1x += p1.x; x1y += p1.y; x1z += p1.z; x1w += p1.w;
        x2x += p2.x; x2y += p2.y; x2z += p2.z; x2w += p2.w;
      }
      sc = 1.f;
    }
    ushort4 y1u, y2u;
    y1u.x = f2bf((x1x * c0.x - x2x * s0.x) * sc);
    y1u.y = f2bf((x1y * c0.y - x2y * s0.y) * sc);
    y1u.z = f2bf((x1z * c0.z - x2z * s0.z) * sc);
    y1u.w = f2bf((x1w * c0.w - x2w * s0.w) * sc);
    y2u.x = f2bf((x2x * c1.x + x1x * s1.x) * sc);
    y2u.y = f2bf((x2y * c1.y + x1y * s1.y) * sc);
    y2u.z = f2bf((x2z * c1.z + x1z * s1.z) * sc);
    y2u.w = f2bf((x2w * c1.w + x1w * s1.w) * sc);
    *(ushort4*)&qkv[base + d] = y1u;
    *(ushort4*)&qkv[base + 64 + d] = y2u;
  } else {
    int t2 = t - (1 << 21);
    int s = t2 & 2047;
    int d = (t2 >> 11) & 127;
    int kvb = t2 >> 18;  // b*4+kv
    size_t off = (size_t)((kvb >> 2) * S_ + s) * 1024 + 512 + (kvb & 3) * 128 + d;
    float v = bias[4096 + (kvb & 3) * 128 + d];
    for (int kc = 0; kc < kparts; ++kc)
      v += part[(size_t)kc * 4194304 + off];
    vT[t2] = f2bf(v);
  }
}

// ---------------- fused RoPE + V-transpose (fallback path, reads qkv only) ----------------
__global__ __launch_bounds__(256) void rope_vtrans_kernel(
    u16* __restrict__ qkv, const float* __restrict__ cosb,
    const float* __restrict__ sinb, u16* __restrict__ vT) {
  int t = blockIdx.x * 256 + threadIdx.x;  // 2^22 total
  if (t < (1 << 21)) {
    int d = (t & 15) << 2;
    int hs = (t >> 4) & 31;
    int s = (t >> 9) & 2047;
    int b = t >> 20;
    size_t base = (size_t)(b * S_ + s) * QKVW_ + hs * HD_;
    float4 c0 = *(const float4*)&cosb[s * HD_ + d];
    float4 s0 = *(const float4*)&sinb[s * HD_ + d];
    float4 c1 = *(const float4*)&cosb[s * HD_ + 64 + d];
    float4 s1 = *(const float4*)&sinb[s * HD_ + 64 + d];
    ushort4 x1u = *(const ushort4*)&qkv[base + d];
    ushort4 x2u = *(const ushort4*)&qkv[base + 64 + d];
    float sc = (hs < NH_) ? SCALING_ : 1.f;
    float x1x = bf2f(x1u.x), x1y = bf2f(x1u.y), x1z = bf2f(x1u.z), x1w = bf2f(x1u.w);
    float x2x = bf2f(x2u.x), x2y = bf2f(x2u.y), x2z = bf2f(x2u.z), x2w = bf2f(x2u.w);
    ushort4 y1u, y2u;
    y1u.x = f2bf((x1x * c0.x - x2x * s0.x) * sc);
    y1u.y = f2bf((x1y * c0.y - x2y * s0.y) * sc);
    y1u.z = f2bf((x1z * c0.z - x2z * s0.z) * sc);
    y1u.w = f2bf((x1w * c0.w - x2w * s0.w) * sc);
    y2u.x = f2bf((x2x * c1.x + x1x * s1.x) * sc);
    y2u.y = f2bf((x2y * c1.y + x1y * s1.y) * sc);
    y2u.z = f2bf((x2z * c1.z + x1z * s1.z) * sc);
    y2u.w = f2bf((x2w * c1.w + x1w * s1.w) * sc);
    *(ushort4*)&qkv[base + d] = y1u;
    *(ushort4*)&qkv[base + 64 + d] = y2u;
  } else {
    t -= (1 << 21);
    int s = t & 2047;
    int d = (t >> 11) & 127;
    int kvb = t >> 18;
    vT[t] = qkv[(size_t)((kvb >> 2) * S_ + s) * QKVW_
                + (HID_ + NKV_ * HD_) + (kvb & 3) * HD_ + d];
  }
}

// ---------------- flash attention (dbuf + 1 barrier/tile) ----------------
// R13 probe: __launch_bounds__(256,3) — 12 waves/CU (was 8). Register accounting
// (oacc 64 + sa 32 + aq 32 + temps ~40 ≈ 168) fits the 170-reg budget of 3
// waves/SIMD; extra TLP should hide the softmax VALU chain + LDS latency.
// Failure signature: VGPR_Count <= 128 + WRITE_SIZE jump = spill -> revert.
__global__ __launch_bounds__(256, 3)
void attn_kernel(const u16* __restrict__ qkv, const u16* __restrict__ vT,
                 u16* __restrict__ out) {
  __shared__ u16 smem[40960] __attribute__((aligned(16)));
  // [0] K buf0 | [8192] K buf1 | [16384] V buf0 | [24576] V buf1 | [32768] P
  u16* p_sm = smem + 32768;
  const int tid = threadIdx.x;
  const int wave = tid >> 6, lane = tid & 63;
  const int lrow = lane & 15, lquad = lane >> 4;
  const int qt = 15 - (int)blockIdx.y;  // LPT: heavy tiles dispatched first
  const int bh = blockIdx.x;
  const int b = bh / NH_, h = bh % NH_, kv = h / NREP_;

  const u16* kbase = qkv + (size_t)(b * S_) * QKVW_ + HID_ + kv * HD_;
  const u16* vbase = vT + (size_t)(b * NKV_ + kv) * HD_ * S_;

  auto stage = [&](int k0, u16* k_d, u16* v_d) {
#pragma unroll
    for (int is = 0; is < 4; ++is) {
      int kr = is * 16 + (tid >> 4);
      int kcs = (((tid & 15) ^ (kr & 7)) << 3);
      gl_lds16(kbase + (size_t)(k0 + kr) * QKVW_ + kcs, k_d + is * 2048 + wave * 512);
      int vr = is * 32 + (tid >> 3);
      int vcs = (((tid & 7) ^ (vr & 7)) << 3);
      gl_lds16(vbase + (size_t)vr * S_ + k0 + vcs, v_d + is * 2048 + wave * 512);
    }
  };

  stage(0, smem, smem + 16384);

  bf16x8 aq[2][4];
  {
    const u16* qrow = qkv + (size_t)(b * S_ + qt * 128 + wave * 32) * QKVW_ + h * HD_;
#pragma unroll
    for (int rg = 0; rg < 2; ++rg)
#pragma unroll
      for (int ks = 0; ks < 4; ++ks)
        aq[rg][ks] = *(const bf16x8*)(qrow + (size_t)(rg * 16 + lrow) * QKVW_ + ks * 32 + lquad * 8);
  }

  f32x4 oacc[2][8] = {};
  float m_run[2], l_run[2];
#pragma unroll
  for (int rg = 0; rg < 2; ++rg) { m_run[rg] = -1e30f; l_run[rg] = 0.f; }

  const int nkt = 2 * qt + 2;
  for (int kt = 0; kt < nkt; ++kt) {
    const int cur = kt & 1;
    u16* k_c = smem + cur * 8192;
    u16* v_c = smem + 16384 + cur * 8192;
    const int k0 = kt * 64;

    asm volatile("s_waitcnt vmcnt(0)" ::: "memory");
    __builtin_amdgcn_s_barrier();
    __builtin_amdgcn_sched_barrier(0);
    if (kt + 1 < nkt)
      stage(k0 + 64, smem + (cur ^ 1) * 8192, smem + 16384 + (cur ^ 1) * 8192);

    f32x4 sa[2][4] = {};
#pragma unroll
    for (int ks = 0; ks < 4; ++ks) {
      bf16x8 kb[4];
#pragma unroll
      for (int cg = 0; cg < 4; ++cg) {
        int row = cg * 16 + lrow;
        int g = (ks * 4 + lquad) ^ (row & 7);
        kb[cg] = *(const bf16x8*)&k_c[row * 128 + g * 8];
      }
      __builtin_amdgcn_s_setprio(1);
#pragma unroll
      for (int rg = 0; rg < 2; ++rg)
#pragma unroll
        for (int cg = 0; cg < 4; ++cg)
          sa[rg][cg] = __builtin_amdgcn_mfma_f32_16x16x32_bf16(kb[cg], aq[rg][ks], sa[rg][cg], 0, 0, 0);
      __builtin_amdgcn_s_setprio(0);
    }

    if (kt >= 2 * qt) {
#pragma unroll
      for (int rg = 0; rg < 2; ++rg) {
        int qg = qt * 128 + wave * 32 + rg * 16 + lrow;
#pragma unroll
        for (int cg = 0; cg < 4; ++cg) {
          int kg = k0 + cg * 16 + lquad * 4;
#pragma unroll
          for (int r = 0; r < 4; ++r)
            if (kg + r > qg) sa[rg][cg][r] -= 1e9f;
        }
      }
    }

    float mt[2];
#pragma unroll
    for (int rg = 0; rg < 2; ++rg) {
      float mv = fmaxf(fmaxf(sa[rg][0][0], sa[rg][0][1]), fmaxf(sa[rg][0][2], sa[rg][0][3]));
#pragma unroll
      for (int cg = 1; cg < 4; ++cg) {
        mv = fmaxf(mv, fmaxf(fmaxf(sa[rg][cg][0], sa[rg][cg][1]),
                             fmaxf(sa[rg][cg][2], sa[rg][cg][3])));
      }
      mv = fmaxf(mv, __shfl_xor(mv, 16));
      mv = fmaxf(mv, __shfl_xor(mv, 32));
      mt[rg] = mv;
    }
    float need = fmaxf(mt[0] - m_run[0], mt[1] - m_run[1]);
    if (!__all(need <= 8.0f)) {  // wave-uniform rescale (defer-max, T13)
      float al[2];
#pragma unroll
      for (int rg = 0; rg < 2; ++rg) {
        float mn = fmaxf(m_run[rg], mt[rg]);
        al[rg] = __expf(m_run[rg] - mn);
        m_run[rg] = mn;
        l_run[rg] *= al[rg];
      }
#pragma unroll
      for (int rg = 0; rg < 2; ++rg)
#pragma unroll
        for (int r = 0; r < 4; ++r) {
          float alr = __shfl(al[rg], lquad * 4 + r, 16);
#pragma unroll
          for (int dg = 0; dg < 8; ++dg) oacc[rg][dg][r] *= alr;
        }
    }
#pragma unroll
    for (int rg = 0; rg < 2; ++rg) {
      float rs = 0.f;
      uint2 pk[4];
#pragma unroll
      for (int cg = 0; cg < 4; ++cg) {
        float p0 = __expf(sa[rg][cg][0] - m_run[rg]);
        float p1 = __expf(sa[rg][cg][1] - m_run[rg]);
        float p2 = __expf(sa[rg][cg][2] - m_run[rg]);
        float p3 = __expf(sa[rg][cg][3] - m_run[rg]);
        rs += (p0 + p1) + (p2 + p3);
        pk[cg].x = cvtpk_bf16(p0, p1);
        pk[cg].y = cvtpk_bf16(p2, p3);
      }
      rs += __shfl_xor(rs, 16);
      rs += __shfl_xor(rs, 32);
      l_run[rg] += rs;
      int q = wave * 32 + rg * 16 + lrow;
#pragma unroll
      for (int cg = 0; cg < 4; ++cg) {
        int g = (cg * 2 + (lquad >> 1)) ^ (q & 7);
        *(uint2*)&p_sm[q * 64 + g * 8 + (lquad & 1) * 4] = pk[cg];
      }
    }

#pragma unroll
    for (int ks2 = 0; ks2 < 2; ++ks2) {
      bf16x8 pa[2];
#pragma unroll
      for (int rg = 0; rg < 2; ++rg) {
        int q = wave * 32 + rg * 16 + lrow;
        int g = (ks2 * 4 + lquad) ^ (q & 7);
        pa[rg] = *(const bf16x8*)&p_sm[q * 64 + g * 8];
      }
      __builtin_amdgcn_s_setprio(1);
#pragma unroll
      for (int dg = 0; dg < 8; ++dg) {
        int row = dg * 16 + lrow;
        int g = (ks2 * 4 + lquad) ^ (row & 7);
        bf16x8 vb = *(const bf16x8*)&v_c[row * 64 + g * 8];
#pragma unroll
        for (int rg = 0; rg < 2; ++rg)
          oacc[rg][dg] = __builtin_amdgcn_mfma_f32_16x16x32_bf16(pa[rg], vb, oacc[rg][dg], 0, 0, 0);
      }
      __builtin_amdgcn_s_setprio(0);
    }
  }

#pragma unroll
  for (int rg = 0; rg < 2; ++rg) {
    float linv = 1.f / l_run[rg];
#pragma unroll
    for (int r = 0; r < 4; ++r) {
      float inv = __shfl(linv, lquad * 4 + r, 16);
      int qg = qt * 128 + wave * 32 + rg * 16 + lquad * 4 + r;
      u16* ob = out + (size_t)(b * S_ + qg) * HID_ + h * HD_;
#pragma unroll
      for (int dg = 0; dg < 8; ++dg)
        ob[dg * 16 + lrow] = f2bf(oacc[rg][dg][r] * inv);
    }
  }
}

// ---------------- launch ----------------
extern "C" void kernel_launch(void* const* d_in, const int* in_sizes, int n_in,
                              void* d_out, int out_size, void* d_ws, size_t ws_size,
                              hipStream_t stream) {
  const float* hid  = (const float*)d_in[0];
  const float* cosb = (const float*)d_in[1];
  const float* sinb = (const float*)d_in[2];
  // d_in[3] attention_mask: deterministic causal -1e9, applied structurally
  const float* q_w = (const float*)d_in[4];
  const float* q_b = (const float*)d_in[5];
  const float* k_w = (const float*)d_in[6];
  const float* k_b = (const float*)d_in[7];
  const float* v_w = (const float*)d_in[8];
  const float* v_b = (const float*)d_in[9];
  const float* o_w = (const float*)d_in[10];
  float* out = (float*)d_out;

  constexpr size_t OFF_HID  = 0;                       // 4096*3584 bf16 (later attn out)
  constexpr size_t OFF_W    = 29360128;                // 4608*3584 bf16
  constexpr size_t OFF_OW   = OFF_W + 33030144;        // 3584*3584 bf16
  constexpr size_t OFF_QKV  = OFF_OW + 25690112;       // 4096*4608 bf16
  constexpr size_t OFF_VT   = OFF_QKV + 37748736;      // 2*4*128*2048 bf16
  constexpr size_t OFF_BIAS = OFF_VT + 4194304;        // 4608 f32
  constexpr size_t OFF_PART = OFF_BIAS + 18432;        // KV partials
  constexpr size_t WS_HYB4  = OFF_PART + 4ull * 16777216;  // ~197 MB (4 buffers)
  constexpr size_t WS_HYB   = OFF_PART + 16777216;     // ~147 MB (1 buffer, atomic)
  constexpr size_t WS_NEED  = OFF_PART;                // ~130 MB (R9 path)
  constexpr size_t WS_OLD   = OFF_W + 33030144 + 37748736 + 4194304 + 18432;

  char* ws = (char*)d_ws;
  if (ws_size >= WS_HYB4) {
    u16*  hid_b = (u16*)(ws + OFF_HID);
    u16*  w_b   = (u16*)(ws + OFF_W);
    u16*  ow_b  = (u16*)(ws + OFF_OW);
    u16*  qkv   = (u16*)(ws + OFF_QKV);
    u16*  vT    = (u16*)(ws + OFF_VT);
    float* bias = (float*)(ws + OFF_BIAS);
    float* part = (float*)(ws + OFF_PART);
    // 1. casts + bias (no zeroing needed — plain-store partials)
    megacast_kernel<<<43026, 256, 0, stream>>>(
        (const float4*)hid, (const float4*)q_w, (const float4*)k_w,
        (const float4*)v_w, (const float4*)o_w,
        (ushort4*)hid_b, (ushort4*)w_b, (ushort4*)ow_b,
        q_b, k_b, v_b, bias, nullptr);
    // 2. QKV hybrid (Q LPT-first; KV split-K=4, plain stores into 4 buffers)
    qkv_hybrid_kernel<<<480, 512, 0, stream>>>(hid_b, w_b, bias, qkv, part, 4);
    // 3. finalize: Q-rope + K(sum 4 + bias + rope) + vT(sum 4 + bias)
    finalize_kernel<<<16384, 256, 0, stream>>>(qkv, cosb, sinb, part, bias, vT, 4);
    // 4. flash attention
    attn_kernel<<<dim3(B_ * NH_, 16), 256, 0, stream>>>(qkv, vT, hid_b);
    // 5. output projection
    gemm256_kernel<<<(M_ / 256) * (HID_ / 256), 512, 0, stream>>>(
        hid_b, ow_b, nullptr, nullptr, out, M_, HID_, HID_);
  } else if (ws_size >= WS_HYB) {
    // single zeroed buffer + atomics
    u16*  hid_b = (u16*)(ws + OFF_HID);
    u16*  w_b   = (u16*)(ws + OFF_W);
    u16*  ow_b  = (u16*)(ws + OFF_OW);
    u16*  qkv   = (u16*)(ws + OFF_QKV);
    u16*  vT    = (u16*)(ws + OFF_VT);
    float* bias = (float*)(ws + OFF_BIAS);
    float* part = (float*)(ws + OFF_PART);
    megacast_kernel<<<47122, 256, 0, stream>>>(
        (const float4*)hid, (const float4*)q_w, (const float4*)k_w,
        (const float4*)v_w, (const float4*)o_w,
        (ushort4*)hid_b, (ushort4*)w_b, (ushort4*)ow_b,
        q_b, k_b, v_b, bias, (float4*)part);
    qkv_hybrid_kernel<<<480, 512, 0, stream>>>(hid_b, w_b, bias, qkv, part, 1);
    finalize_kernel<<<16384, 256, 0, stream>>>(qkv, cosb, sinb, part, bias, vT, 1);
    attn_kernel<<<dim3(B_ * NH_, 16), 256, 0, stream>>>(qkv, vT, hid_b);
    gemm256_kernel<<<(M_ / 256) * (HID_ / 256), 512, 0, stream>>>(
        hid_b, ow_b, nullptr, nullptr, out, M_, HID_, HID_);
  } else if (ws_size >= WS_NEED) {
    // R9 path
    u16*  hid_b = (u16*)(ws + OFF_HID);
    u16*  w_b   = (u16*)(ws + OFF_W);
    u16*  ow_b  = (u16*)(ws + OFF_OW);
    u16*  qkv   = (u16*)(ws + OFF_QKV);
    u16*  vT    = (u16*)(ws + OFF_VT);
    float* bias = (float*)(ws + OFF_BIAS);
    megacast_kernel<<<43026, 256, 0, stream>>>(
        (const float4*)hid, (const float4*)q_w, (const float4*)k_w,
        (const float4*)v_w, (const float4*)o_w,
        (ushort4*)hid_b, (ushort4*)w_b, (ushort4*)ow_b,
        q_b, k_b, v_b, bias, nullptr);
    gemm_bt_kernel<<<(M_ / 128) * (QKVW_ / 128), 256, 0, stream>>>(
        hid_b, w_b, bias, qkv, nullptr, M_, QKVW_, HID_);
    rope_vtrans_kernel<<<16384, 256, 0, stream>>>(qkv, cosb, sinb, vT);
    attn_kernel<<<dim3(B_ * NH_, 16), 256, 0, stream>>>(qkv, vT, hid_b);
    gemm256_kernel<<<(M_ / 256) * (HID_ / 256), 512, 0, stream>>>(
        hid_b, ow_b, nullptr, nullptr, out, M_, HID_, HID_);
  } else if (ws_size >= WS_OLD) {
    // old 104.4 MB layout, o_w reuses w_b
    u16*  hid_b = (u16*)(ws + OFF_HID);
    u16*  w_b   = (u16*)(ws + OFF_W);
    u16*  qkv   = (u16*)(ws + OFF_W + 33030144);
    u16*  vT    = (u16*)(ws + OFF_W + 33030144 + 37748736);
    float* bias = (float*)(ws + OFF_W + 33030144 + 37748736 + 4194304);
    f2b4_kernel<<<14336, 256, 0, stream>>>((const float4*)hid, (ushort4*)hid_b, 3670016);
    f2b4_kernel<<<12544, 256, 0, stream>>>((const float4*)q_w, (ushort4*)w_b, 3211264);
    f2b4_kernel<<<1792, 256, 0, stream>>>((const float4*)k_w, (ushort4*)(w_b + 12845056), 458752);
    f2b4_kernel<<<1792, 256, 0, stream>>>((const float4*)v_w, (ushort4*)(w_b + 14680064), 458752);
    bias_cat_kernel<<<18, 256, 0, stream>>>(q_b, k_b, v_b, bias);
    gemm_bt_kernel<<<(M_ / 128) * (QKVW_ / 128), 256, 0, stream>>>(
        hid_b, w_b, bias, qkv, nullptr, M_, QKVW_, HID_);
    f2b4_kernel<<<12544, 256, 0, stream>>>((const float4*)o_w, (ushort4*)w_b, 3211264);
    rope_vtrans_kernel<<<16384, 256, 0, stream>>>(qkv, cosb, sinb, vT);
    attn_kernel<<<dim3(B_ * NH_, 16), 256, 0, stream>>>(qkv, vT, hid_b);
    gemm256_kernel<<<(M_ / 256) * (HID_ / 256), 512, 0, stream>>>(
        hid_b, w_b, nullptr, nullptr, out, M_, HID_, HID_);
  }
  // else: fail loudly via absmax
}

// Round 14
// 571.276 us; speedup vs baseline: 1.0652x; 1.0652x over previous
//
#include <hip/hip_runtime.h>
#include <stdint.h>

// Qwen2 attention layer, bf16-MFMA pipeline.
// B=2 S=2048 HID=3584 NH=28 NKV=4 D=128 (GQA rep=7)

typedef unsigned short u16;
typedef __bf16 bf16x8 __attribute__((ext_vector_type(8)));
typedef float f32x4 __attribute__((ext_vector_type(4)));

#define B_      2
#define S_      2048
#define HID_    3584
#define NH_     28
#define NKV_    4
#define HD_     128
#define NREP_   7
#define QKVW_   4608   // 3584 q + 512 k + 512 v
#define M_      4096   // B*S
#define SCALING_ 0.08838834764831843f

__device__ __forceinline__ u16 f2bf(float f) {
  union { float f; unsigned u; } x; x.f = f;
  return (u16)((x.u + 0x7FFFu + ((x.u >> 16) & 1u)) >> 16);
}
__device__ __forceinline__ float bf2f(u16 h) {
  union { unsigned u; float f; } x; x.u = ((unsigned)h) << 16;
  return x.f;
}
// pack 2 f32 -> 2 bf16 in one u32 (lo = a, hi = b), RNE
__device__ __forceinline__ unsigned cvtpk_bf16(float a, float b) {
  unsigned r;
  asm("v_cvt_pk_bf16_f32 %0, %1, %2" : "=v"(r) : "v"(a), "v"(b));
  return r;
}

// async global->LDS, 16B/lane; LDS dest is wave-uniform base + lane*16
__device__ __forceinline__ void gl_lds16(const void* g, void* l) {
  __builtin_amdgcn_global_load_lds(
      (__attribute__((address_space(1))) void*)(g),
      (__attribute__((address_space(3))) void*)(l), 16, 0, 0);
}

__device__ __forceinline__ ushort4 cvt4(float4 v) {
  ushort4 o;
  o.x = f2bf(v.x); o.y = f2bf(v.y); o.z = f2bf(v.z); o.w = f2bf(v.w);
  return o;
}

// ---------------- fp32 -> bf16 cast (standalone, fallback path) ----------------
__global__ __launch_bounds__(256) void f2b4_kernel(
    const float4* __restrict__ in, ushort4* __restrict__ out, int n4) {
  int i = blockIdx.x * 256 + threadIdx.x;
  if (i >= n4) return;
  out[i] = cvt4(in[i]);
}

// ---------------- concat q_b|k_b|v_b (standalone, fallback path) ----------------
__global__ __launch_bounds__(256) void bias_cat_kernel(
    const float* __restrict__ qb, const float* __restrict__ kb,
    const float* __restrict__ vb, float* __restrict__ out) {
  int i = blockIdx.x * 256 + threadIdx.x;
  if (i < 3584) out[i] = qb[i];
  else if (i < 4096) out[i] = kb[i - 3584];
  else if (i < 4608) out[i] = vb[i - 4096];
}

// ---------------- megacast: ALL input casts + bias concat (+ optional part-zero) ----------------
__global__ __launch_bounds__(256) void megacast_kernel(
    const float4* __restrict__ hid, const float4* __restrict__ qw,
    const float4* __restrict__ kw, const float4* __restrict__ vw,
    const float4* __restrict__ ow,
    ushort4* __restrict__ hid_b, ushort4* __restrict__ w_b,
    ushort4* __restrict__ ow_b,
    const float* __restrict__ qb, const float* __restrict__ kb,
    const float* __restrict__ vb, float* __restrict__ bias,
    float4* __restrict__ part_zero) {
  const int blk = blockIdx.x;
  const int tid = threadIdx.x;
  if (blk < 14336) {
    int i = blk * 256 + tid;
    hid_b[i] = cvt4(hid[i]);
  } else if (blk < 26880) {
    int i = (blk - 14336) * 256 + tid;
    w_b[i] = cvt4(qw[i]);
  } else if (blk < 28672) {
    int i = (blk - 26880) * 256 + tid;
    w_b[3211264 + i] = cvt4(kw[i]);
  } else if (blk < 30464) {
    int i = (blk - 28672) * 256 + tid;
    w_b[3670016 + i] = cvt4(vw[i]);
  } else if (blk < 43008) {
    int i = (blk - 30464) * 256 + tid;
    ow_b[i] = cvt4(ow[i]);
  } else if (blk < 43026) {
    int i = (blk - 43008) * 256 + tid;
    if (i < 3584) bias[i] = qb[i];
    else if (i < 4096) bias[i] = kb[i - 3584];
    else if (i < 4608) bias[i] = vb[i - 4096];
  } else {
    int i = (blk - 43026) * 256 + tid;  // 1048576 float4 = 4096x1024 f32
    float4 z = {0.f, 0.f, 0.f, 0.f};
    part_zero[i] = z;
  }
}

// ---------------- QKV hybrid GEMM: 256^2 pipelined, Q full-K + KV split-K=4 ----------------
// LPT: LONG Q tiles at blockIdx [0,224) (first block-wave); short KV chunks at
// [224,480) fill the 32 remaining CUs + the post-Q tail.
// kparts==4 -> KV chunks write PLAIN f32 stores into per-chunk buffer (R12:
// 146->130us vs atomics). kparts==1 -> atomicAdd into zeroed single buffer.
__global__ __launch_bounds__(512, 2)
void qkv_hybrid_kernel(const u16* __restrict__ A, const u16* __restrict__ W,
                       const float* __restrict__ bias, u16* __restrict__ qkv,
                       float* __restrict__ kvpart, int kparts) {
  __shared__ u16 sm[65536] __attribute__((aligned(16)));
  const int tid = threadIdx.x;
  const int wave = tid >> 6, lane = tid & 63;
  const int lrow = lane & 15, lquad = lane >> 4;
  const int wm = wave >> 2, wn = wave & 3;
  const int K = HID_;

  const bool isKV = ((int)blockIdx.x >= 224);
  int m0, n0, kb, kc = 0;
  int nt;
  if (isKV) {
    int bid = (int)blockIdx.x - 224;
    int v = (bid & 7) * 32 + (bid >> 3);   // XCD remap over 256
    int tile = v & 63;                     // 16 m x 4 n
    kc = v >> 6;                           // 0..3
    m0 = (tile >> 2) << 8;
    n0 = 3584 + ((tile & 3) << 8);
    kb = kc * 896;
    nt = 14;                               // 896 / 64
  } else {
    int bid = (int)blockIdx.x;
    int v = (bid & 7) * 28 + (bid >> 3);   // XCD remap over 224
    m0 = (v / 14) << 8;
    n0 = (v % 14) << 8;
    kb = 0;
    nt = 56;                               // 3584 / 64
  }

  const int srow = tid >> 3, sg = tid & 7;
  const int aRowBase[4] = {0, 128, 64, 192};   // issue order Aq0, Aq2, Aq1, Aq3
  size_t srcB[4], srcA[4];
  int dstA[4];
#pragma unroll
  for (int o = 0; o < 4; ++o) {
    int rB = o * 64 + srow;
    srcB[o] = (size_t)(n0 + rB) * K + ((sg ^ (rB & 7)) << 3) + kb;
    int rA = aRowBase[o] + srow;
    srcA[o] = (size_t)(m0 + rA) * K + ((sg ^ (rA & 7)) << 3) + kb;
    dstA[o] = aRowBase[o] * 64 + wave * 512;
  }

#pragma unroll
  for (int o = 0; o < 4; ++o)
    gl_lds16(W + srcB[o], sm + 32768 + o * 4096 + wave * 512);
#pragma unroll
  for (int o = 0; o < 4; ++o)
    gl_lds16(A + srcA[o], sm + dstA[o]);

  f32x4 acc[8][4] = {};
  for (int t = 0; t < nt; ++t) {
    const int cur = t & 1, nxt = cur ^ 1;
    const u16* Ab = sm + cur * 16384;
    const u16* Bb = sm + 32768 + cur * 16384;
    u16* An = sm + nxt * 16384;
    u16* Bn = sm + 32768 + nxt * 16384;
    const bool pf = (t + 1 < nt);
    const size_t k1 = (size_t)(t + 1) << 6;

    asm volatile("s_waitcnt vmcnt(2)" ::: "memory");
    __builtin_amdgcn_s_barrier();
    __builtin_amdgcn_sched_barrier(0);

    bf16x8 bfr[4][2], af[4];
    // phase 0
    if (pf) {
      gl_lds16(W + (srcB[0] + k1), Bn + 0 * 4096 + wave * 512);
      gl_lds16(W + (srcB[1] + k1), Bn + 1 * 4096 + wave * 512);
    }
#pragma unroll
    for (int nf = 0; nf < 4; ++nf) {
      int rb = wn * 64 + nf * 16 + lrow;
      bfr[nf][0] = *(const bf16x8*)&Bb[rb * 64 + ((lquad ^ (rb & 7)) << 3)];
    }
#pragma unroll
    for (int j = 0; j < 4; ++j) {
      int ra = wm * 128 + j * 16 + lrow;
      af[j] = *(const bf16x8*)&Ab[ra * 64 + ((lquad ^ (ra & 7)) << 3)];
    }
    __builtin_amdgcn_s_setprio(1);
#pragma unroll
    for (int j = 0; j < 4; ++j)
#pragma unroll
      for (int nf = 0; nf < 4; ++nf)
        acc[j][nf] = __builtin_amdgcn_mfma_f32_16x16x32_bf16(af[j], bfr[nf][0], acc[j][nf], 0, 0, 0);
    __builtin_amdgcn_s_setprio(0);

    // phase 1
    if (pf) {
      gl_lds16(W + (srcB[2] + k1), Bn + 2 * 4096 + wave * 512);
      gl_lds16(W + (srcB[3] + k1), Bn + 3 * 4096 + wave * 512);
    }
#pragma unroll
    for (int nf = 0; nf < 4; ++nf) {
      int rb = wn * 64 + nf * 16 + lrow;
      bfr[nf][1] = *(const bf16x8*)&Bb[rb * 64 + (((4 + lquad) ^ (rb & 7)) << 3)];
    }
#pragma unroll
    for (int j = 0; j < 4; ++j) {
      int ra = wm * 128 + j * 16 + lrow;
      af[j] = *(const bf16x8*)&Ab[ra * 64 + (((4 + lquad) ^ (ra & 7)) << 3)];
    }
    __builtin_amdgcn_s_setprio(1);
#pragma unroll
    for (int j = 0; j < 4; ++j)
#pragma unroll
      for (int nf = 0; nf < 4; ++nf)
        acc[j][nf] = __builtin_amdgcn_mfma_f32_16x16x32_bf16(af[j], bfr[nf][1], acc[j][nf], 0, 0, 0);
    __builtin_amdgcn_s_setprio(0);

    // phase 2 entry
    if (pf) asm volatile("s_waitcnt vmcnt(4)" ::: "memory");
    else    asm volatile("s_waitcnt vmcnt(0)" ::: "memory");
    __builtin_amdgcn_s_barrier();
    __builtin_amdgcn_sched_barrier(0);

    // phase 2
    if (pf) {
      gl_lds16(A + (srcA[0] + k1), An + dstA[0]);
      gl_lds16(A + (srcA[1] + k1), An + dstA[1]);
    }
#pragma unroll
    for (int j = 0; j < 4; ++j) {
      int ra = wm * 128 + 64 + j * 16 + lrow;
      af[j] = *(const bf16x8*)&Ab[ra * 64 + ((lquad ^ (ra & 7)) << 3)];
    }
    __builtin_amdgcn_s_setprio(1);
#pragma unroll
    for (int j = 0; j < 4; ++j)
#pragma unroll
      for (int nf = 0; nf < 4; ++nf)
        acc[4 + j][nf] = __builtin_amdgcn_mfma_f32_16x16x32_bf16(af[j], bfr[nf][0], acc[4 + j][nf], 0, 0, 0);
    __builtin_amdgcn_s_setprio(0);

    // phase 3
    if (pf) {
      gl_lds16(A + (srcA[2] + k1), An + dstA[2]);
      gl_lds16(A + (srcA[3] + k1), An + dstA[3]);
    }
#pragma unroll
    for (int j = 0; j < 4; ++j) {
      int ra = wm * 128 + 64 + j * 16 + lrow;
      af[j] = *(const bf16x8*)&Ab[ra * 64 + (((4 + lquad) ^ (ra & 7)) << 3)];
    }
    __builtin_amdgcn_s_setprio(1);
#pragma unroll
    for (int j = 0; j < 4; ++j)
#pragma unroll
      for (int nf = 0; nf < 4; ++nf)
        acc[4 + j][nf] = __builtin_amdgcn_mfma_f32_16x16x32_bf16(af[j], bfr[nf][1], acc[4 + j][nf], 0, 0, 0);
    __builtin_amdgcn_s_setprio(0);
  }

  // epilogue: C/D layout col=lane&15, row=(lane>>4)*4+reg
  if (isKV) {
    const int cbase = n0 - 3584;
    if (kparts == 4) {
      float* dst = kvpart + (size_t)kc * 4194304;
#pragma unroll
      for (int mf = 0; mf < 8; ++mf) {
        int row = m0 + wm * 128 + mf * 16 + lquad * 4;
#pragma unroll
        for (int nf = 0; nf < 4; ++nf) {
          int col = cbase + wn * 64 + nf * 16 + lrow;
#pragma unroll
          for (int r = 0; r < 4; ++r)
            dst[(size_t)(row + r) * 1024 + col] = acc[mf][nf][r];
        }
      }
    } else {
#pragma unroll
      for (int mf = 0; mf < 8; ++mf) {
        int row = m0 + wm * 128 + mf * 16 + lquad * 4;
#pragma unroll
        for (int nf = 0; nf < 4; ++nf) {
          int col = cbase + wn * 64 + nf * 16 + lrow;
#pragma unroll
          for (int r = 0; r < 4; ++r)
            atomicAdd(&kvpart[(size_t)(row + r) * 1024 + col], acc[mf][nf][r]);
        }
      }
    }
  } else {
#pragma unroll
    for (int mf = 0; mf < 8; ++mf) {
      int row = m0 + wm * 128 + mf * 16 + lquad * 4;
#pragma unroll
      for (int nf = 0; nf < 4; ++nf) {
        int col = n0 + wn * 64 + nf * 16 + lrow;
        float bv = bias[col];
#pragma unroll
        for (int r = 0; r < 4; ++r)
          qkv[(size_t)(row + r) * QKVW_ + col] = f2bf(acc[mf][nf][r] + bv);
      }
    }
  }
}

// ---------------- GEMM-BT 128x128 (fallback QKV) ----------------
__global__ __launch_bounds__(256, 2)
void gemm_bt_kernel(const u16* __restrict__ A, const u16* __restrict__ W,
                    const float* __restrict__ bias,
                    u16* __restrict__ outb, float* __restrict__ outf,
                    int M, int N, int K) {
  __shared__ u16 sm[16384] __attribute__((aligned(16)));  // A 128x64 | B 128x64
  u16* a_sm = sm;
  u16* b_sm = sm + 8192;
  const int tid = threadIdx.x;
  const int wave = tid >> 6, lane = tid & 63;
  const int lrow = lane & 15, lquad = lane >> 4;
  const int nmt = M >> 7, nnt = N >> 7, nwg = nmt * nnt;
  const int chunk = nwg >> 3;
  const int v = ((int)blockIdx.x & 7) * chunk + ((int)blockIdx.x >> 3);
  const int grp = v / (4 * nnt);
  const int rem = v - grp * (4 * nnt);
  const int m0 = (grp * 4 + (rem & 3)) << 7;
  const int n0 = (rem >> 2) << 7;
  const int wr = (wave >> 1) * 64, wc = (wave & 1) * 64;

  const u16* Asrc[4];
  const u16* Bsrc[4];
#pragma unroll
  for (int is = 0; is < 4; ++is) {
    int row = is * 32 + (tid >> 3);
    int col = (((tid & 7) ^ (row & 7)) << 3);
    Asrc[is] = A + (size_t)(m0 + row) * K + col;
    Bsrc[is] = W + (size_t)(n0 + row) * K + col;
  }

  f32x4 acc[4][4] = {};
  for (int k0 = 0; k0 < K; k0 += 64) {
#pragma unroll
    for (int is = 0; is < 4; ++is) {
      gl_lds16(Asrc[is] + k0, a_sm + is * 2048 + wave * 512);
      gl_lds16(Bsrc[is] + k0, b_sm + is * 2048 + wave * 512);
    }
    __syncthreads();
#pragma unroll
    for (int ks = 0; ks < 2; ++ks) {
      bf16x8 af[4], bfr[4];
#pragma unroll
      for (int g4 = 0; g4 < 4; ++g4) {
        int ra = wr + g4 * 16 + lrow;
        af[g4] = *(const bf16x8*)&a_sm[ra * 64 + (((ks * 4 + lquad) ^ (ra & 7)) << 3)];
        int rb = wc + g4 * 16 + lrow;
        bfr[g4] = *(const bf16x8*)&b_sm[rb * 64 + (((ks * 4 + lquad) ^ (rb & 7)) << 3)];
      }
#pragma unroll
      for (int i = 0; i < 4; ++i)
#pragma unroll
        for (int j = 0; j < 4; ++j)
          acc[i][j] = __builtin_amdgcn_mfma_f32_16x16x32_bf16(af[i], bfr[j], acc[i][j], 0, 0, 0);
    }
    __syncthreads();
  }
#pragma unroll
  for (int i = 0; i < 4; ++i) {
    int row = m0 + wr + i * 16 + lquad * 4;
#pragma unroll
    for (int j = 0; j < 4; ++j) {
      int col = n0 + wc + j * 16 + lrow;
      float bv = bias ? bias[col] : 0.f;
#pragma unroll
      for (int r = 0; r < 4; ++r) {
        float v2 = acc[i][j][r] + bv;
        if (outb) outb[(size_t)(row + r) * N + col] = f2bf(v2);
        else      outf[(size_t)(row + r) * N + col] = v2;
      }
    }
  }
}

// ---------------- GEMM-BT 256x256, pipelined (O-proj: 224 blocks, 1 wave) ----------------
__global__ __launch_bounds__(512, 2)
void gemm256_kernel(const u16* __restrict__ A, const u16* __restrict__ W,
                    const float* __restrict__ bias,
                    u16* __restrict__ outb, float* __restrict__ outf,
                    int M, int N, int K) {
  __shared__ u16 sm[65536] __attribute__((aligned(16)));
  const int tid = threadIdx.x;
  const int wave = tid >> 6, lane = tid & 63;
  const int lrow = lane & 15, lquad = lane >> 4;
  const int wm = wave >> 2, wn = wave & 3;
  const int nmt = M >> 8, nnt = N >> 8, nwg = nmt * nnt;
  const int chunk = nwg >> 3;
  const int v = ((int)blockIdx.x & 7) * chunk + ((int)blockIdx.x >> 3);
  const int m0 = (v / nnt) << 8;
  const int n0 = (v % nnt) << 8;

  const int srow = tid >> 3, sg = tid & 7;
  const int aRowBase[4] = {0, 128, 64, 192};
  size_t srcB[4], srcA[4];
  int dstA[4];
#pragma unroll
  for (int o = 0; o < 4; ++o) {
    int rB = o * 64 + srow;
    srcB[o] = (size_t)(n0 + rB) * K + ((sg ^ (rB & 7)) << 3);
    int rA = aRowBase[o] + srow;
    srcA[o] = (size_t)(m0 + rA) * K + ((sg ^ (rA & 7)) << 3);
    dstA[o] = aRowBase[o] * 64 + wave * 512;
  }

#pragma unroll
  for (int o = 0; o < 4; ++o)
    gl_lds16(W + srcB[o], sm + 32768 + o * 4096 + wave * 512);
#pragma unroll
  for (int o = 0; o < 4; ++o)
    gl_lds16(A + srcA[o], sm + dstA[o]);

  f32x4 acc[8][4] = {};
  const int nt = K >> 6;
  for (int t = 0; t < nt; ++t) {
    const int cur = t & 1, nxt = cur ^ 1;
    const u16* Ab = sm + cur * 16384;
    const u16* Bb = sm + 32768 + cur * 16384;
    u16* An = sm + nxt * 16384;
    u16* Bn = sm + 32768 + nxt * 16384;
    const bool pf = (t + 1 < nt);
    const size_t k1 = (size_t)(t + 1) << 6;

    asm volatile("s_waitcnt vmcnt(2)" ::: "memory");
    __builtin_amdgcn_s_barrier();
    __builtin_amdgcn_sched_barrier(0);

    bf16x8 bfr[4][2], af[4];
    // phase 0
    if (pf) {
      gl_lds16(W + (srcB[0] + k1), Bn + 0 * 4096 + wave * 512);
      gl_lds16(W + (srcB[1] + k1), Bn + 1 * 4096 + wave * 512);
    }
#pragma unroll
    for (int nf = 0; nf < 4; ++nf) {
      int rb = wn * 64 + nf * 16 + lrow;
      bfr[nf][0] = *(const bf16x8*)&Bb[rb * 64 + ((lquad ^ (rb & 7)) << 3)];
    }
#pragma unroll
    for (int j = 0; j < 4; ++j) {
      int ra = wm * 128 + j * 16 + lrow;
      af[j] = *(const bf16x8*)&Ab[ra * 64 + ((lquad ^ (ra & 7)) << 3)];
    }
    __builtin_amdgcn_s_setprio(1);
#pragma unroll
    for (int j = 0; j < 4; ++j)
#pragma unroll
      for (int nf = 0; nf < 4; ++nf)
        acc[j][nf] = __builtin_amdgcn_mfma_f32_16x16x32_bf16(af[j], bfr[nf][0], acc[j][nf], 0, 0, 0);
    __builtin_amdgcn_s_setprio(0);

    // phase 1
    if (pf) {
      gl_lds16(W + (srcB[2] + k1), Bn + 2 * 4096 + wave * 512);
      gl_lds16(W + (srcB[3] + k1), Bn + 3 * 4096 + wave * 512);
    }
#pragma unroll
    for (int nf = 0; nf < 4; ++nf) {
      int rb = wn * 64 + nf * 16 + lrow;
      bfr[nf][1] = *(const bf16x8*)&Bb[rb * 64 + (((4 + lquad) ^ (rb & 7)) << 3)];
    }
#pragma unroll
    for (int j = 0; j < 4; ++j) {
      int ra = wm * 128 + j * 16 + lrow;
      af[j] = *(const bf16x8*)&Ab[ra * 64 + (((4 + lquad) ^ (ra & 7)) << 3)];
    }
    __builtin_amdgcn_s_setprio(1);
#pragma unroll
    for (int j = 0; j < 4; ++j)
#pragma unroll
      for (int nf = 0; nf < 4; ++nf)
        acc[j][nf] = __builtin_amdgcn_mfma_f32_16x16x32_bf16(af[j], bfr[nf][1], acc[j][nf], 0, 0, 0);
    __builtin_amdgcn_s_setprio(0);

    // phase 2 entry
    if (pf) asm volatile("s_waitcnt vmcnt(4)" ::: "memory");
    else    asm volatile("s_waitcnt vmcnt(0)" ::: "memory");
    __builtin_amdgcn_s_barrier();
    __builtin_amdgcn_sched_barrier(0);

    // phase 2
    if (pf) {
      gl_lds16(A + (srcA[0] + k1), An + dstA[0]);
      gl_lds16(A + (srcA[1] + k1), An + dstA[1]);
    }
#pragma unroll
    for (int j = 0; j < 4; ++j) {
      int ra = wm * 128 + 64 + j * 16 + lrow;
      af[j] = *(const bf16x8*)&Ab[ra * 64 + ((lquad ^ (ra & 7)) << 3)];
    }
    __builtin_amdgcn_s_setprio(1);
#pragma unroll
    for (int j = 0; j < 4; ++j)
#pragma unroll
      for (int nf = 0; nf < 4; ++nf)
        acc[4 + j][nf] = __builtin_amdgcn_mfma_f32_16x16x32_bf16(af[j], bfr[nf][0], acc[4 + j][nf], 0, 0, 0);
    __builtin_amdgcn_s_setprio(0);

    // phase 3
    if (pf) {
      gl_lds16(A + (srcA[2] + k1), An + dstA[2]);
      gl_lds16(A + (srcA[3] + k1), An + dstA[3]);
    }
#pragma unroll
    for (int j = 0; j < 4; ++j) {
      int ra = wm * 128 + 64 + j * 16 + lrow;
      af[j] = *(const bf16x8*)&Ab[ra * 64 + (((4 + lquad) ^ (ra & 7)) << 3)];
    }
    __builtin_amdgcn_s_setprio(1);
#pragma unroll
    for (int j = 0; j < 4; ++j)
#pragma unroll
      for (int nf = 0; nf < 4; ++nf)
        acc[4 + j][nf] = __builtin_amdgcn_mfma_f32_16x16x32_bf16(af[j], bfr[nf][1], acc[4 + j][nf], 0, 0, 0);
    __builtin_amdgcn_s_setprio(0);
  }

#pragma unroll
  for (int mf = 0; mf < 8; ++mf) {
    int row = m0 + wm * 128 + mf * 16 + lquad * 4;
#pragma unroll
    for (int nf = 0; nf < 4; ++nf) {
      int col = n0 + wn * 64 + nf * 16 + lrow;
      float bv = bias ? bias[col] : 0.f;
#pragma unroll
      for (int r = 0; r < 4; ++r) {
        float val = acc[mf][nf][r] + bv;
        if (outb) outb[(size_t)(row + r) * N + col] = f2bf(val);
        else      outf[(size_t)(row + r) * N + col] = val;
      }
    }
  }
}

// ---------------- finalize: Q-rope + K (sum partials + bias + rope) + vT (sum partials) ----------------
__global__ __launch_bounds__(256) void finalize_kernel(
    u16* __restrict__ qkv, const float* __restrict__ cosb,
    const float* __restrict__ sinb, const float* __restrict__ part,
    const float* __restrict__ bias, u16* __restrict__ vT, int kparts) {
  int t = blockIdx.x * 256 + threadIdx.x;  // 2^22 total
  if (t < (1 << 21)) {
    int d = (t & 15) << 2;        // 0,4,...,60
    int hs = (t >> 4) & 31;
    int s = (t >> 9) & 2047;
    int b = t >> 20;
    size_t base = (size_t)(b * S_ + s) * QKVW_ + hs * HD_;
    float4 c0 = *(const float4*)&cosb[s * HD_ + d];
    float4 s0 = *(const float4*)&sinb[s * HD_ + d];
    float4 c1 = *(const float4*)&cosb[s * HD_ + 64 + d];
    float4 s1 = *(const float4*)&sinb[s * HD_ + 64 + d];
    float x1x, x1y, x1z, x1w, x2x, x2y, x2z, x2w, sc;
    if (hs < NH_) {
      ushort4 x1u = *(const ushort4*)&qkv[base + d];
      ushort4 x2u = *(const ushort4*)&qkv[base + 64 + d];
      sc = SCALING_;
      x1x = bf2f(x1u.x); x1y = bf2f(x1u.y); x1z = bf2f(x1u.z); x1w = bf2f(x1u.w);
      x2x = bf2f(x2u.x); x2y = bf2f(x2u.y); x2z = bf2f(x2u.z); x2w = bf2f(x2u.w);
    } else {
      int pc = (hs - 28) * 128;
      size_t prow = (size_t)(b * S_ + s) * 1024;
      float4 b1 = *(const float4*)&bias[3584 + pc + d];
      float4 b2 = *(const float4*)&bias[3584 + pc + 64 + d];
      x1x = b1.x; x1y = b1.y; x1z = b1.z; x1w = b1.w;
      x2x = b2.x; x2y = b2.y; x2z = b2.z; x2w = b2.w;
      for (int kc = 0; kc < kparts; ++kc) {
        const float* pb = part + (size_t)kc * 4194304;
        float4 p1 = *(const float4*)&pb[prow + pc + d];
        float4 p2 = *(const float4*)&pb[prow + pc + 64 + d];
        x1x += p1.x; x1y += p1.y; x1z += p1.z; x1w += p1.w;
        x2x += p2.x; x2y += p2.y; x2z += p2.z; x2w += p2.w;
      }
      sc = 1.f;
    }
    ushort4 y1u, y2u;
    y1u.x = f2bf((x1x * c0.x - x2x * s0.x) * sc);
    y1u.y = f2bf((x1y * c0.y - x2y * s0.y) * sc);
    y1u.z = f2bf((x1z * c0.z - x2z * s0.z) * sc);
    y1u.w = f2bf((x1w * c0.w - x2w * s0.w) * sc);
    y2u.x = f2bf((x2x * c1.x + x1x * s1.x) * sc);
    y2u.y = f2bf((x2y * c1.y + x1y * s1.y) * sc);
    y2u.z = f2bf((x2z * c1.z + x1z * s1.z) * sc);
    y2u.w = f2bf((x2w * c1.w + x1w * s1.w) * sc);
    *(ushort4*)&qkv[base + d] = y1u;
    *(ushort4*)&qkv[base + 64 + d] = y2u;
  } else {
    int t2 = t - (1 << 21);
    int s = t2 & 2047;
    int d = (t2 >> 11) & 127;
    int kvb = t2 >> 18;  // b*4+kv
    size_t off = (size_t)((kvb >> 2) * S_ + s) * 1024 + 512 + (kvb & 3) * 128 + d;
    float v = bias[4096 + (kvb & 3) * 128 + d];
    for (int kc = 0; kc < kparts; ++kc)
      v += part[(size_t)kc * 4194304 + off];
    vT[t2] = f2bf(v);
  }
}

// ---------------- fused RoPE + V-transpose (fallback path, reads qkv only) ----------------
__global__ __launch_bounds__(256) void rope_vtrans_kernel(
    u16* __restrict__ qkv, const float* __restrict__ cosb,
    const float* __restrict__ sinb, u16* __restrict__ vT) {
  int t = blockIdx.x * 256 + threadIdx.x;  // 2^22 total
  if (t < (1 << 21)) {
    int d = (t & 15) << 2;
    int hs = (t >> 4) & 31;
    int s = (t >> 9) & 2047;
    int b = t >> 20;
    size_t base = (size_t)(b * S_ + s) * QKVW_ + hs * HD_;
    float4 c0 = *(const float4*)&cosb[s * HD_ + d];
    float4 s0 = *(const float4*)&sinb[s * HD_ + d];
    float4 c1 = *(const float4*)&cosb[s * HD_ + 64 + d];
    float4 s1 = *(const float4*)&sinb[s * HD_ + 64 + d];
    ushort4 x1u = *(const ushort4*)&qkv[base + d];
    ushort4 x2u = *(const ushort4*)&qkv[base + 64 + d];
    float sc = (hs < NH_) ? SCALING_ : 1.f;
    float x1x = bf2f(x1u.x), x1y = bf2f(x1u.y), x1z = bf2f(x1u.z), x1w = bf2f(x1u.w);
    float x2x = bf2f(x2u.x), x2y = bf2f(x2u.y), x2z = bf2f(x2u.z), x2w = bf2f(x2u.w);
    ushort4 y1u, y2u;
    y1u.x = f2bf((x1x * c0.x - x2x * s0.x) * sc);
    y1u.y = f2bf((x1y * c0.y - x2y * s0.y) * sc);
    y1u.z = f2bf((x1z * c0.z - x2z * s0.z) * sc);
    y1u.w = f2bf((x1w * c0.w - x2w * s0.w) * sc);
    y2u.x = f2bf((x2x * c1.x + x1x * s1.x) * sc);
    y2u.y = f2bf((x2y * c1.y + x1y * s1.y) * sc);
    y2u.z = f2bf((x2z * c1.z + x1z * s1.z) * sc);
    y2u.w = f2bf((x2w * c1.w + x1w * s1.w) * sc);
    *(ushort4*)&qkv[base + d] = y1u;
    *(ushort4*)&qkv[base + 64 + d] = y2u;
  } else {
    t -= (1 << 21);
    int s = t & 2047;
    int d = (t >> 11) & 127;
    int kvb = t >> 18;
    vT[t] = qkv[(size_t)((kvb >> 2) * S_ + s) * QKVW_
                + (HID_ + NKV_ * HD_) + (kvb & 3) * HD_ + d];
  }
}

// ---------------- flash attention (dbuf + 1 barrier/tile) ----------------
// (256,2) is the measured optimum: (256,4) spilled (R2), (256,3) blew the LDS
// allocation granule to 80KB and dropped occupancy to 10.5% (R13: 144us).
__global__ __launch_bounds__(256, 2)
void attn_kernel(const u16* __restrict__ qkv, const u16* __restrict__ vT,
                 u16* __restrict__ out) {
  __shared__ u16 smem[40960] __attribute__((aligned(16)));
  // [0] K buf0 | [8192] K buf1 | [16384] V buf0 | [24576] V buf1 | [32768] P
  u16* p_sm = smem + 32768;
  const int tid = threadIdx.x;
  const int wave = tid >> 6, lane = tid & 63;
  const int lrow = lane & 15, lquad = lane >> 4;
  const int qt = 15 - (int)blockIdx.y;  // LPT: heavy tiles dispatched first
  const int bh = blockIdx.x;
  const int b = bh / NH_, h = bh % NH_, kv = h / NREP_;

  const u16* kbase = qkv + (size_t)(b * S_) * QKVW_ + HID_ + kv * HD_;
  const u16* vbase = vT + (size_t)(b * NKV_ + kv) * HD_ * S_;

  auto stage = [&](int k0, u16* k_d, u16* v_d) {
#pragma unroll
    for (int is = 0; is < 4; ++is) {
      int kr = is * 16 + (tid >> 4);
      int kcs = (((tid & 15) ^ (kr & 7)) << 3);
      gl_lds16(kbase + (size_t)(k0 + kr) * QKVW_ + kcs, k_d + is * 2048 + wave * 512);
      int vr = is * 32 + (tid >> 3);
      int vcs = (((tid & 7) ^ (vr & 7)) << 3);
      gl_lds16(vbase + (size_t)vr * S_ + k0 + vcs, v_d + is * 2048 + wave * 512);
    }
  };

  stage(0, smem, smem + 16384);

  bf16x8 aq[2][4];
  {
    const u16* qrow = qkv + (size_t)(b * S_ + qt * 128 + wave * 32) * QKVW_ + h * HD_;
#pragma unroll
    for (int rg = 0; rg < 2; ++rg)
#pragma unroll
      for (int ks = 0; ks < 4; ++ks)
        aq[rg][ks] = *(const bf16x8*)(qrow + (size_t)(rg * 16 + lrow) * QKVW_ + ks * 32 + lquad * 8);
  }

  f32x4 oacc[2][8] = {};
  float m_run[2], l_run[2];
#pragma unroll
  for (int rg = 0; rg < 2; ++rg) { m_run[rg] = -1e30f; l_run[rg] = 0.f; }

  const int nkt = 2 * qt + 2;
  for (int kt = 0; kt < nkt; ++kt) {
    const int cur = kt & 1;
    u16* k_c = smem + cur * 8192;
    u16* v_c = smem + 16384 + cur * 8192;
    const int k0 = kt * 64;

    asm volatile("s_waitcnt vmcnt(0)" ::: "memory");
    __builtin_amdgcn_s_barrier();
    __builtin_amdgcn_sched_barrier(0);
    if (kt + 1 < nkt)
      stage(k0 + 64, smem + (cur ^ 1) * 8192, smem + 16384 + (cur ^ 1) * 8192);

    f32x4 sa[2][4] = {};
#pragma unroll
    for (int ks = 0; ks < 4; ++ks) {
      bf16x8 kb[4];
#pragma unroll
      for (int cg = 0; cg < 4; ++cg) {
        int row = cg * 16 + lrow;
        int g = (ks * 4 + lquad) ^ (row & 7);
        kb[cg] = *(const bf16x8*)&k_c[row * 128 + g * 8];
      }
      __builtin_amdgcn_s_setprio(1);
#pragma unroll
      for (int rg = 0; rg < 2; ++rg)
#pragma unroll
        for (int cg = 0; cg < 4; ++cg)
          sa[rg][cg] = __builtin_amdgcn_mfma_f32_16x16x32_bf16(kb[cg], aq[rg][ks], sa[rg][cg], 0, 0, 0);
      __builtin_amdgcn_s_setprio(0);
    }

    if (kt >= 2 * qt) {
#pragma unroll
      for (int rg = 0; rg < 2; ++rg) {
        int qg = qt * 128 + wave * 32 + rg * 16 + lrow;
#pragma unroll
        for (int cg = 0; cg < 4; ++cg) {
          int kg = k0 + cg * 16 + lquad * 4;
#pragma unroll
          for (int r = 0; r < 4; ++r)
            if (kg + r > qg) sa[rg][cg][r] -= 1e9f;
        }
      }
    }

    float mt[2];
#pragma unroll
    for (int rg = 0; rg < 2; ++rg) {
      float mv = fmaxf(fmaxf(sa[rg][0][0], sa[rg][0][1]), fmaxf(sa[rg][0][2], sa[rg][0][3]));
#pragma unroll
      for (int cg = 1; cg < 4; ++cg) {
        mv = fmaxf(mv, fmaxf(fmaxf(sa[rg][cg][0], sa[rg][cg][1]),
                             fmaxf(sa[rg][cg][2], sa[rg][cg][3])));
      }
      mv = fmaxf(mv, __shfl_xor(mv, 16));
      mv = fmaxf(mv, __shfl_xor(mv, 32));
      mt[rg] = mv;
    }
    float need = fmaxf(mt[0] - m_run[0], mt[1] - m_run[1]);
    if (!__all(need <= 8.0f)) {  // wave-uniform rescale (defer-max, T13)
      float al[2];
#pragma unroll
      for (int rg = 0; rg < 2; ++rg) {
        float mn = fmaxf(m_run[rg], mt[rg]);
        al[rg] = __expf(m_run[rg] - mn);
        m_run[rg] = mn;
        l_run[rg] *= al[rg];
      }
#pragma unroll
      for (int rg = 0; rg < 2; ++rg)
#pragma unroll
        for (int r = 0; r < 4; ++r) {
          float alr = __shfl(al[rg], lquad * 4 + r, 16);
#pragma unroll
          for (int dg = 0; dg < 8; ++dg) oacc[rg][dg][r] *= alr;
        }
    }
#pragma unroll
    for (int rg = 0; rg < 2; ++rg) {
      float rs = 0.f;
      uint2 pk[4];
#pragma unroll
      for (int cg = 0; cg < 4; ++cg) {
        float p0 = __expf(sa[rg][cg][0] - m_run[rg]);
        float p1 = __expf(sa[rg][cg][1] - m_run[rg]);
        float p2 = __expf(sa[rg][cg][2] - m_run[rg]);
        float p3 = __expf(sa[rg][cg][3] - m_run[rg]);
        rs += (p0 + p1) + (p2 + p3);
        pk[cg].x = cvtpk_bf16(p0, p1);
        pk[cg].y = cvtpk_bf16(p2, p3);
      }
      rs += __shfl_xor(rs, 16);
      rs += __shfl_xor(rs, 32);
      l_run[rg] += rs;
      int q = wave * 32 + rg * 16 + lrow;
#pragma unroll
      for (int cg = 0; cg < 4; ++cg) {
        int g = (cg * 2 + (lquad >> 1)) ^ (q & 7);
        *(uint2*)&p_sm[q * 64 + g * 8 + (lquad & 1) * 4] = pk[cg];
      }
    }

#pragma unroll
    for (int ks2 = 0; ks2 < 2; ++ks2) {
      bf16x8 pa[2];
#pragma unroll
      for (int rg = 0; rg < 2; ++rg) {
        int q = wave * 32 + rg * 16 + lrow;
        int g = (ks2 * 4 + lquad) ^ (q & 7);
        pa[rg] = *(const bf16x8*)&p_sm[q * 64 + g * 8];
      }
      __builtin_amdgcn_s_setprio(1);
#pragma unroll
      for (int dg = 0; dg < 8; ++dg) {
        int row = dg * 16 + lrow;
        int g = (ks2 * 4 + lquad) ^ (row & 7);
        bf16x8 vb = *(const bf16x8*)&v_c[row * 64 + g * 8];
#pragma unroll
        for (int rg = 0; rg < 2; ++rg)
          oacc[rg][dg] = __builtin_amdgcn_mfma_f32_16x16x32_bf16(pa[rg], vb, oacc[rg][dg], 0, 0, 0);
      }
      __builtin_amdgcn_s_setprio(0);
    }
  }

#pragma unroll
  for (int rg = 0; rg < 2; ++rg) {
    float linv = 1.f / l_run[rg];
#pragma unroll
    for (int r = 0; r < 4; ++r) {
      float inv = __shfl(linv, lquad * 4 + r, 16);
      int qg = qt * 128 + wave * 32 + rg * 16 + lquad * 4 + r;
      u16* ob = out + (size_t)(b * S_ + qg) * HID_ + h * HD_;
#pragma unroll
      for (int dg = 0; dg < 8; ++dg)
        ob[dg * 16 + lrow] = f2bf(oacc[rg][dg][r] * inv);
    }
  }
}

// ---------------- launch ----------------
extern "C" void kernel_launch(void* const* d_in, const int* in_sizes, int n_in,
                              void* d_out, int out_size, void* d_ws, size_t ws_size,
                              hipStream_t stream) {
  const float* hid  = (const float*)d_in[0];
  const float* cosb = (const float*)d_in[1];
  const float* sinb = (const float*)d_in[2];
  // d_in[3] attention_mask: deterministic causal -1e9, applied structurally
  const float* q_w = (const float*)d_in[4];
  const float* q_b = (const float*)d_in[5];
  const float* k_w = (const float*)d_in[6];
  const float* k_b = (const float*)d_in[7];
  const float* v_w = (const float*)d_in[8];
  const float* v_b = (const float*)d_in[9];
  const float* o_w = (const float*)d_in[10];
  float* out = (float*)d_out;

  constexpr size_t OFF_HID  = 0;                       // 4096*3584 bf16 (later attn out)
  constexpr size_t OFF_W    = 29360128;                // 4608*3584 bf16
  constexpr size_t OFF_OW   = OFF_W + 33030144;        // 3584*3584 bf16
  constexpr size_t OFF_QKV  = OFF_OW + 25690112;       // 4096*4608 bf16
  constexpr size_t OFF_VT   = OFF_QKV + 37748736;      // 2*4*128*2048 bf16
  constexpr size_t OFF_BIAS = OFF_VT + 4194304;        // 4608 f32
  constexpr size_t OFF_PART = OFF_BIAS + 18432;        // KV partials
  constexpr size_t WS_HYB4  = OFF_PART + 4ull * 16777216;  // ~197 MB (4 buffers)
  constexpr size_t WS_HYB   = OFF_PART + 16777216;     // ~147 MB (1 buffer, atomic)
  constexpr size_t WS_NEED  = OFF_PART;                // ~130 MB (R9 path)
  constexpr size_t WS_OLD   = OFF_W + 33030144 + 37748736 + 4194304 + 18432;

  char* ws = (char*)d_ws;
  if (ws_size >= WS_HYB4) {
    u16*  hid_b = (u16*)(ws + OFF_HID);
    u16*  w_b   = (u16*)(ws + OFF_W);
    u16*  ow_b  = (u16*)(ws + OFF_OW);
    u16*  qkv   = (u16*)(ws + OFF_QKV);
    u16*  vT    = (u16*)(ws + OFF_VT);
    float* bias = (float*)(ws + OFF_BIAS);
    float* part = (float*)(ws + OFF_PART);
    // 1. casts + bias (no zeroing needed — plain-store partials)
    megacast_kernel<<<43026, 256, 0, stream>>>(
        (const float4*)hid, (const float4*)q_w, (const float4*)k_w,
        (const float4*)v_w, (const float4*)o_w,
        (ushort4*)hid_b, (ushort4*)w_b, (ushort4*)ow_b,
        q_b, k_b, v_b, bias, nullptr);
    // 2. QKV hybrid (Q LPT-first; KV split-K=4, plain stores into 4 buffers)
    qkv_hybrid_kernel<<<480, 512, 0, stream>>>(hid_b, w_b, bias, qkv, part, 4);
    // 3. finalize: Q-rope + K(sum 4 + bias + rope) + vT(sum 4 + bias)
    finalize_kernel<<<16384, 256, 0, stream>>>(qkv, cosb, sinb, part, bias, vT, 4);
    // 4. flash attention
    attn_kernel<<<dim3(B_ * NH_, 16), 256, 0, stream>>>(qkv, vT, hid_b);
    // 5. output projection
    gemm256_kernel<<<(M_ / 256) * (HID_ / 256), 512, 0, stream>>>(
        hid_b, ow_b, nullptr, nullptr, out, M_, HID_, HID_);
  } else if (ws_size >= WS_HYB) {
    // single zeroed buffer + atomics
    u16*  hid_b = (u16*)(ws + OFF_HID);
    u16*  w_b   = (u16*)(ws + OFF_W);
    u16*  ow_b  = (u16*)(ws + OFF_OW);
    u16*  qkv   = (u16*)(ws + OFF_QKV);
    u16*  vT    = (u16*)(ws + OFF_VT);
    float* bias = (float*)(ws + OFF_BIAS);
    float* part = (float*)(ws + OFF_PART);
    megacast_kernel<<<47122, 256, 0, stream>>>(
        (const float4*)hid, (const float4*)q_w, (const float4*)k_w,
        (const float4*)v_w, (const float4*)o_w,
        (ushort4*)hid_b, (ushort4*)w_b, (ushort4*)ow_b,
        q_b, k_b, v_b, bias, (float4*)part);
    qkv_hybrid_kernel<<<480, 512, 0, stream>>>(hid_b, w_b, bias, qkv, part, 1);
    finalize_kernel<<<16384, 256, 0, stream>>>(qkv, cosb, sinb, part, bias, vT, 1);
    attn_kernel<<<dim3(B_ * NH_, 16), 256, 0, stream>>>(qkv, vT, hid_b);
    gemm256_kernel<<<(M_ / 256) * (HID_ / 256), 512, 0, stream>>>(
        hid_b, ow_b, nullptr, nullptr, out, M_, HID_, HID_);
  } else if (ws_size >= WS_NEED) {
    // R9 path
    u16*  hid_b = (u16*)(ws + OFF_HID);
    u16*  w_b   = (u16*)(ws + OFF_W);
    u16*  ow_b  = (u16*)(ws + OFF_OW);
    u16*  qkv   = (u16*)(ws + OFF_QKV);
    u16*  vT    = (u16*)(ws + OFF_VT);
    float* bias = (float*)(ws + OFF_BIAS);
    megacast_kernel<<<43026, 256, 0, stream>>>(
        (const float4*)hid, (const float4*)q_w, (const float4*)k_w,
        (const float4*)v_w, (const float4*)o_w,
        (ushort4*)hid_b, (ushort4*)w_b, (ushort4*)ow_b,
        q_b, k_b, v_b, bias, nullptr);
    gemm_bt_kernel<<<(M_ / 128) * (QKVW_ / 128), 256, 0, stream>>>(
        hid_b, w_b, bias, qkv, nullptr, M_, QKVW_, HID_);
    rope_vtrans_kernel<<<16384, 256, 0, stream>>>(qkv, cosb, sinb, vT);
    attn_kernel<<<dim3(B_ * NH_, 16), 256, 0, stream>>>(qkv, vT, hid_b);
    gemm256_kernel<<<(M_ / 256) * (HID_ / 256), 512, 0, stream>>>(
        hid_b, ow_b, nullptr, nullptr, out, M_, HID_, HID_);
  } else if (ws_size >= WS_OLD) {
    // old 104.4 MB layout, o_w reuses w_b
    u16*  hid_b = (u16*)(ws + OFF_HID);
    u16*  w_b   = (u16*)(ws + OFF_W);
    u16*  qkv   = (u16*)(ws + OFF_W + 33030144);
    u16*  vT    = (u16*)(ws + OFF_W + 33030144 + 37748736);
    float* bias = (float*)(ws + OFF_W + 33030144 + 37748736 + 4194304);
    f2b4_kernel<<<14336, 256, 0, stream>>>((const float4*)hid, (ushort4*)hid_b, 3670016);
    f2b4_kernel<<<12544, 256, 0, stream>>>((const float4*)q_w, (ushort4*)w_b, 3211264);
    f2b4_kernel<<<1792, 256, 0, stream>>>((const float4*)k_w, (ushort4*)(w_b + 12845056), 458752);
    f2b4_kernel<<<1792, 256, 0, stream>>>((const float4*)v_w, (ushort4*)(w_b + 14680064), 458752);
    bias_cat_kernel<<<18, 256, 0, stream>>>(q_b, k_b, v_b, bias);
    gemm_bt_kernel<<<(M_ / 128) * (QKVW_ / 128), 256, 0, stream>>>(
        hid_b, w_b, bias, qkv, nullptr, M_, QKVW_, HID_);
    f2b4_kernel<<<12544, 256, 0, stream>>>((const float4*)o_w, (ushort4*)w_b, 3211264);
    rope_vtrans_kernel<<<16384, 256, 0, stream>>>(qkv, cosb, sinb, vT);
    attn_kernel<<<dim3(B_ * NH_, 16), 256, 0, stream>>>(qkv, vT, hid_b);
    gemm256_kernel<<<(M_ / 256) * (HID_ / 256), 512, 0, stream>>>(
        hid_b, w_b, nullptr, nullptr, out, M_, HID_, HID_);
  }
  // else: fail loudly via absmax
}

// Round 15
// 564.745 us; speedup vs baseline: 1.0775x; 1.0116x over previous
//
#include <hip/hip_runtime.h>
#include <stdint.h>

// Qwen2 attention layer, bf16-MFMA pipeline.
// B=2 S=2048 HID=3584 NH=28 NKV=4 D=128 (GQA rep=7)

typedef unsigned short u16;
typedef __bf16 bf16x8 __attribute__((ext_vector_type(8)));
typedef float f32x4 __attribute__((ext_vector_type(4)));

#define B_      2
#define S_      2048
#define HID_    3584
#define NH_     28
#define NKV_    4
#define HD_     128
#define NREP_   7
#define QKVW_   4608   // 3584 q + 512 k + 512 v
#define M_      4096   // B*S
#define SCALING_ 0.08838834764831843f

__device__ __forceinline__ u16 f2bf(float f) {
  union { float f; unsigned u; } x; x.f = f;
  return (u16)((x.u + 0x7FFFu + ((x.u >> 16) & 1u)) >> 16);
}
__device__ __forceinline__ float bf2f(u16 h) {
  union { unsigned u; float f; } x; x.u = ((unsigned)h) << 16;
  return x.f;
}
// pack 2 f32 -> 2 bf16 in one u32 (lo = a, hi = b), RNE
__device__ __forceinline__ unsigned cvtpk_bf16(float a, float b) {
  unsigned r;
  asm("v_cvt_pk_bf16_f32 %0, %1, %2" : "=v"(r) : "v"(a), "v"(b));
  return r;
}

// async global->LDS, 16B/lane; LDS dest is wave-uniform base + lane*16
__device__ __forceinline__ void gl_lds16(const void* g, void* l) {
  __builtin_amdgcn_global_load_lds(
      (__attribute__((address_space(1))) void*)(g),
      (__attribute__((address_space(3))) void*)(l), 16, 0, 0);
}

__device__ __forceinline__ ushort4 cvt4(float4 v) {
  ushort4 o;
  o.x = f2bf(v.x); o.y = f2bf(v.y); o.z = f2bf(v.z); o.w = f2bf(v.w);
  return o;
}

// ---------------- fp32 -> bf16 cast (standalone, fallback path) ----------------
__global__ __launch_bounds__(256) void f2b4_kernel(
    const float4* __restrict__ in, ushort4* __restrict__ out, int n4) {
  int i = blockIdx.x * 256 + threadIdx.x;
  if (i >= n4) return;
  out[i] = cvt4(in[i]);
}

// ---------------- concat q_b|k_b|v_b (standalone, fallback path) ----------------
__global__ __launch_bounds__(256) void bias_cat_kernel(
    const float* __restrict__ qb, const float* __restrict__ kb,
    const float* __restrict__ vb, float* __restrict__ out) {
  int i = blockIdx.x * 256 + threadIdx.x;
  if (i < 3584) out[i] = qb[i];
  else if (i < 4096) out[i] = kb[i - 3584];
  else if (i < 4608) out[i] = vb[i - 4096];
}

// ---------------- megacast: ALL input casts + bias concat (+ optional part-zero) ----------------
__global__ __launch_bounds__(256) void megacast_kernel(
    const float4* __restrict__ hid, const float4* __restrict__ qw,
    const float4* __restrict__ kw, const float4* __restrict__ vw,
    const float4* __restrict__ ow,
    ushort4* __restrict__ hid_b, ushort4* __restrict__ w_b,
    ushort4* __restrict__ ow_b,
    const float* __restrict__ qb, const float* __restrict__ kb,
    const float* __restrict__ vb, float* __restrict__ bias,
    float4* __restrict__ part_zero) {
  const int blk = blockIdx.x;
  const int tid = threadIdx.x;
  if (blk < 14336) {
    int i = blk * 256 + tid;
    hid_b[i] = cvt4(hid[i]);
  } else if (blk < 26880) {
    int i = (blk - 14336) * 256 + tid;
    w_b[i] = cvt4(qw[i]);
  } else if (blk < 28672) {
    int i = (blk - 26880) * 256 + tid;
    w_b[3211264 + i] = cvt4(kw[i]);
  } else if (blk < 30464) {
    int i = (blk - 28672) * 256 + tid;
    w_b[3670016 + i] = cvt4(vw[i]);
  } else if (blk < 43008) {
    int i = (blk - 30464) * 256 + tid;
    ow_b[i] = cvt4(ow[i]);
  } else if (blk < 43026) {
    int i = (blk - 43008) * 256 + tid;
    if (i < 3584) bias[i] = qb[i];
    else if (i < 4096) bias[i] = kb[i - 3584];
    else if (i < 4608) bias[i] = vb[i - 4096];
  } else {
    int i = (blk - 43026) * 256 + tid;  // 1048576 float4 = 4096x1024 f32
    float4 z = {0.f, 0.f, 0.f, 0.f};
    part_zero[i] = z;
  }
}

// ---------------- QKV hybrid GEMM: 256^2 pipelined, Q full-K + KV split-K=4 ----------------
// LPT: LONG Q tiles at blockIdx [0,224) (first block-wave); short KV chunks at
// [224,480) fill the 32 remaining CUs + the post-Q tail.
// kparts==4 -> KV chunks write PLAIN f32 stores into per-chunk buffer (R12:
// 146->130us vs atomics). kparts==1 -> atomicAdd into zeroed single buffer.
__global__ __launch_bounds__(512, 2)
void qkv_hybrid_kernel(const u16* __restrict__ A, const u16* __restrict__ W,
                       const float* __restrict__ bias, u16* __restrict__ qkv,
                       float* __restrict__ kvpart, int kparts) {
  __shared__ u16 sm[65536] __attribute__((aligned(16)));
  const int tid = threadIdx.x;
  const int wave = tid >> 6, lane = tid & 63;
  const int lrow = lane & 15, lquad = lane >> 4;
  const int wm = wave >> 2, wn = wave & 3;
  const int K = HID_;

  const bool isKV = ((int)blockIdx.x >= 224);
  int m0, n0, kb, kc = 0;
  int nt;
  if (isKV) {
    int bid = (int)blockIdx.x - 224;
    int v = (bid & 7) * 32 + (bid >> 3);   // XCD remap over 256
    int tile = v & 63;                     // 16 m x 4 n
    kc = v >> 6;                           // 0..3
    m0 = (tile >> 2) << 8;
    n0 = 3584 + ((tile & 3) << 8);
    kb = kc * 896;
    nt = 14;                               // 896 / 64
  } else {
    int bid = (int)blockIdx.x;
    int v = (bid & 7) * 28 + (bid >> 3);   // XCD remap over 224
    m0 = (v / 14) << 8;
    n0 = (v % 14) << 8;
    kb = 0;
    nt = 56;                               // 3584 / 64
  }

  const int srow = tid >> 3, sg = tid & 7;
  const int aRowBase[4] = {0, 128, 64, 192};   // issue order Aq0, Aq2, Aq1, Aq3
  size_t srcB[4], srcA[4];
  int dstA[4];
#pragma unroll
  for (int o = 0; o < 4; ++o) {
    int rB = o * 64 + srow;
    srcB[o] = (size_t)(n0 + rB) * K + ((sg ^ (rB & 7)) << 3) + kb;
    int rA = aRowBase[o] + srow;
    srcA[o] = (size_t)(m0 + rA) * K + ((sg ^ (rA & 7)) << 3) + kb;
    dstA[o] = aRowBase[o] * 64 + wave * 512;
  }

#pragma unroll
  for (int o = 0; o < 4; ++o)
    gl_lds16(W + srcB[o], sm + 32768 + o * 4096 + wave * 512);
#pragma unroll
  for (int o = 0; o < 4; ++o)
    gl_lds16(A + srcA[o], sm + dstA[o]);

  f32x4 acc[8][4] = {};
  for (int t = 0; t < nt; ++t) {
    const int cur = t & 1, nxt = cur ^ 1;
    const u16* Ab = sm + cur * 16384;
    const u16* Bb = sm + 32768 + cur * 16384;
    u16* An = sm + nxt * 16384;
    u16* Bn = sm + 32768 + nxt * 16384;
    const bool pf = (t + 1 < nt);
    const size_t k1 = (size_t)(t + 1) << 6;

    asm volatile("s_waitcnt vmcnt(2)" ::: "memory");
    __builtin_amdgcn_s_barrier();
    __builtin_amdgcn_sched_barrier(0);

    bf16x8 bfr[4][2], af[4];
    // phase 0
    if (pf) {
      gl_lds16(W + (srcB[0] + k1), Bn + 0 * 4096 + wave * 512);
      gl_lds16(W + (srcB[1] + k1), Bn + 1 * 4096 + wave * 512);
    }
#pragma unroll
    for (int nf = 0; nf < 4; ++nf) {
      int rb = wn * 64 + nf * 16 + lrow;
      bfr[nf][0] = *(const bf16x8*)&Bb[rb * 64 + ((lquad ^ (rb & 7)) << 3)];
    }
#pragma unroll
    for (int j = 0; j < 4; ++j) {
      int ra = wm * 128 + j * 16 + lrow;
      af[j] = *(const bf16x8*)&Ab[ra * 64 + ((lquad ^ (ra & 7)) << 3)];
    }
    __builtin_amdgcn_s_setprio(1);
#pragma unroll
    for (int j = 0; j < 4; ++j)
#pragma unroll
      for (int nf = 0; nf < 4; ++nf)
        acc[j][nf] = __builtin_amdgcn_mfma_f32_16x16x32_bf16(af[j], bfr[nf][0], acc[j][nf], 0, 0, 0);
    __builtin_amdgcn_s_setprio(0);

    // phase 1
    if (pf) {
      gl_lds16(W + (srcB[2] + k1), Bn + 2 * 4096 + wave * 512);
      gl_lds16(W + (srcB[3] + k1), Bn + 3 * 4096 + wave * 512);
    }
#pragma unroll
    for (int nf = 0; nf < 4; ++nf) {
      int rb = wn * 64 + nf * 16 + lrow;
      bfr[nf][1] = *(const bf16x8*)&Bb[rb * 64 + (((4 + lquad) ^ (rb & 7)) << 3)];
    }
#pragma unroll
    for (int j = 0; j < 4; ++j) {
      int ra = wm * 128 + j * 16 + lrow;
      af[j] = *(const bf16x8*)&Ab[ra * 64 + (((4 + lquad) ^ (ra & 7)) << 3)];
    }
    __builtin_amdgcn_s_setprio(1);
#pragma unroll
    for (int j = 0; j < 4; ++j)
#pragma unroll
      for (int nf = 0; nf < 4; ++nf)
        acc[j][nf] = __builtin_amdgcn_mfma_f32_16x16x32_bf16(af[j], bfr[nf][1], acc[j][nf], 0, 0, 0);
    __builtin_amdgcn_s_setprio(0);

    // phase 2 entry
    if (pf) asm volatile("s_waitcnt vmcnt(4)" ::: "memory");
    else    asm volatile("s_waitcnt vmcnt(0)" ::: "memory");
    __builtin_amdgcn_s_barrier();
    __builtin_amdgcn_sched_barrier(0);

    // phase 2
    if (pf) {
      gl_lds16(A + (srcA[0] + k1), An + dstA[0]);
      gl_lds16(A + (srcA[1] + k1), An + dstA[1]);
    }
#pragma unroll
    for (int j = 0; j < 4; ++j) {
      int ra = wm * 128 + 64 + j * 16 + lrow;
      af[j] = *(const bf16x8*)&Ab[ra * 64 + ((lquad ^ (ra & 7)) << 3)];
    }
    __builtin_amdgcn_s_setprio(1);
#pragma unroll
    for (int j = 0; j < 4; ++j)
#pragma unroll
      for (int nf = 0; nf < 4; ++nf)
        acc[4 + j][nf] = __builtin_amdgcn_mfma_f32_16x16x32_bf16(af[j], bfr[nf][0], acc[4 + j][nf], 0, 0, 0);
    __builtin_amdgcn_s_setprio(0);

    // phase 3
    if (pf) {
      gl_lds16(A + (srcA[2] + k1), An + dstA[2]);
      gl_lds16(A + (srcA[3] + k1), An + dstA[3]);
    }
#pragma unroll
    for (int j = 0; j < 4; ++j) {
      int ra = wm * 128 + 64 + j * 16 + lrow;
      af[j] = *(const bf16x8*)&Ab[ra * 64 + (((4 + lquad) ^ (ra & 7)) << 3)];
    }
    __builtin_amdgcn_s_setprio(1);
#pragma unroll
    for (int j = 0; j < 4; ++j)
#pragma unroll
      for (int nf = 0; nf < 4; ++nf)
        acc[4 + j][nf] = __builtin_amdgcn_mfma_f32_16x16x32_bf16(af[j], bfr[nf][1], acc[4 + j][nf], 0, 0, 0);
    __builtin_amdgcn_s_setprio(0);
  }

  // epilogue: C/D layout col=lane&15, row=(lane>>4)*4+reg
  if (isKV) {
    const int cbase = n0 - 3584;
    if (kparts == 4) {
      float* dst = kvpart + (size_t)kc * 4194304;
#pragma unroll
      for (int mf = 0; mf < 8; ++mf) {
        int row = m0 + wm * 128 + mf * 16 + lquad * 4;
#pragma unroll
        for (int nf = 0; nf < 4; ++nf) {
          int col = cbase + wn * 64 + nf * 16 + lrow;
#pragma unroll
          for (int r = 0; r < 4; ++r)
            dst[(size_t)(row + r) * 1024 + col] = acc[mf][nf][r];
        }
      }
    } else {
#pragma unroll
      for (int mf = 0; mf < 8; ++mf) {
        int row = m0 + wm * 128 + mf * 16 + lquad * 4;
#pragma unroll
        for (int nf = 0; nf < 4; ++nf) {
          int col = cbase + wn * 64 + nf * 16 + lrow;
#pragma unroll
          for (int r = 0; r < 4; ++r)
            atomicAdd(&kvpart[(size_t)(row + r) * 1024 + col], acc[mf][nf][r]);
        }
      }
    }
  } else {
#pragma unroll
    for (int mf = 0; mf < 8; ++mf) {
      int row = m0 + wm * 128 + mf * 16 + lquad * 4;
#pragma unroll
      for (int nf = 0; nf < 4; ++nf) {
        int col = n0 + wn * 64 + nf * 16 + lrow;
        float bv = bias[col];
#pragma unroll
        for (int r = 0; r < 4; ++r)
          qkv[(size_t)(row + r) * QKVW_ + col] = f2bf(acc[mf][nf][r] + bv);
      }
    }
  }
}

// ---------------- GEMM-BT 128x128 (fallback QKV) ----------------
__global__ __launch_bounds__(256, 2)
void gemm_bt_kernel(const u16* __restrict__ A, const u16* __restrict__ W,
                    const float* __restrict__ bias,
                    u16* __restrict__ outb, float* __restrict__ outf,
                    int M, int N, int K) {
  __shared__ u16 sm[16384] __attribute__((aligned(16)));  // A 128x64 | B 128x64
  u16* a_sm = sm;
  u16* b_sm = sm + 8192;
  const int tid = threadIdx.x;
  const int wave = tid >> 6, lane = tid & 63;
  const int lrow = lane & 15, lquad = lane >> 4;
  const int nmt = M >> 7, nnt = N >> 7, nwg = nmt * nnt;
  const int chunk = nwg >> 3;
  const int v = ((int)blockIdx.x & 7) * chunk + ((int)blockIdx.x >> 3);
  const int grp = v / (4 * nnt);
  const int rem = v - grp * (4 * nnt);
  const int m0 = (grp * 4 + (rem & 3)) << 7;
  const int n0 = (rem >> 2) << 7;
  const int wr = (wave >> 1) * 64, wc = (wave & 1) * 64;

  const u16* Asrc[4];
  const u16* Bsrc[4];
#pragma unroll
  for (int is = 0; is < 4; ++is) {
    int row = is * 32 + (tid >> 3);
    int col = (((tid & 7) ^ (row & 7)) << 3);
    Asrc[is] = A + (size_t)(m0 + row) * K + col;
    Bsrc[is] = W + (size_t)(n0 + row) * K + col;
  }

  f32x4 acc[4][4] = {};
  for (int k0 = 0; k0 < K; k0 += 64) {
#pragma unroll
    for (int is = 0; is < 4; ++is) {
      gl_lds16(Asrc[is] + k0, a_sm + is * 2048 + wave * 512);
      gl_lds16(Bsrc[is] + k0, b_sm + is * 2048 + wave * 512);
    }
    __syncthreads();
#pragma unroll
    for (int ks = 0; ks < 2; ++ks) {
      bf16x8 af[4], bfr[4];
#pragma unroll
      for (int g4 = 0; g4 < 4; ++g4) {
        int ra = wr + g4 * 16 + lrow;
        af[g4] = *(const bf16x8*)&a_sm[ra * 64 + (((ks * 4 + lquad) ^ (ra & 7)) << 3)];
        int rb = wc + g4 * 16 + lrow;
        bfr[g4] = *(const bf16x8*)&b_sm[rb * 64 + (((ks * 4 + lquad) ^ (rb & 7)) << 3)];
      }
#pragma unroll
      for (int i = 0; i < 4; ++i)
#pragma unroll
        for (int j = 0; j < 4; ++j)
          acc[i][j] = __builtin_amdgcn_mfma_f32_16x16x32_bf16(af[i], bfr[j], acc[i][j], 0, 0, 0);
    }
    __syncthreads();
  }
#pragma unroll
  for (int i = 0; i < 4; ++i) {
    int row = m0 + wr + i * 16 + lquad * 4;
#pragma unroll
    for (int j = 0; j < 4; ++j) {
      int col = n0 + wc + j * 16 + lrow;
      float bv = bias ? bias[col] : 0.f;
#pragma unroll
      for (int r = 0; r < 4; ++r) {
        float v2 = acc[i][j][r] + bv;
        if (outb) outb[(size_t)(row + r) * N + col] = f2bf(v2);
        else      outf[(size_t)(row + r) * N + col] = v2;
      }
    }
  }
}

// ---------------- GEMM-BT 256x256, pipelined (O-proj: 224 blocks, 1 wave) ----------------
__global__ __launch_bounds__(512, 2)
void gemm256_kernel(const u16* __restrict__ A, const u16* __restrict__ W,
                    const float* __restrict__ bias,
                    u16* __restrict__ outb, float* __restrict__ outf,
                    int M, int N, int K) {
  __shared__ u16 sm[65536] __attribute__((aligned(16)));
  const int tid = threadIdx.x;
  const int wave = tid >> 6, lane = tid & 63;
  const int lrow = lane & 15, lquad = lane >> 4;
  const int wm = wave >> 2, wn = wave & 3;
  const int nmt = M >> 8, nnt = N >> 8, nwg = nmt * nnt;
  const int chunk = nwg >> 3;
  const int v = ((int)blockIdx.x & 7) * chunk + ((int)blockIdx.x >> 3);
  const int m0 = (v / nnt) << 8;
  const int n0 = (v % nnt) << 8;

  const int srow = tid >> 3, sg = tid & 7;
  const int aRowBase[4] = {0, 128, 64, 192};
  size_t srcB[4], srcA[4];
  int dstA[4];
#pragma unroll
  for (int o = 0; o < 4; ++o) {
    int rB = o * 64 + srow;
    srcB[o] = (size_t)(n0 + rB) * K + ((sg ^ (rB & 7)) << 3);
    int rA = aRowBase[o] + srow;
    srcA[o] = (size_t)(m0 + rA) * K + ((sg ^ (rA & 7)) << 3);
    dstA[o] = aRowBase[o] * 64 + wave * 512;
  }

#pragma unroll
  for (int o = 0; o < 4; ++o)
    gl_lds16(W + srcB[o], sm + 32768 + o * 4096 + wave * 512);
#pragma unroll
  for (int o = 0; o < 4; ++o)
    gl_lds16(A + srcA[o], sm + dstA[o]);

  f32x4 acc[8][4] = {};
  const int nt = K >> 6;
  for (int t = 0; t < nt; ++t) {
    const int cur = t & 1, nxt = cur ^ 1;
    const u16* Ab = sm + cur * 16384;
    const u16* Bb = sm + 32768 + cur * 16384;
    u16* An = sm + nxt * 16384;
    u16* Bn = sm + 32768 + nxt * 16384;
    const bool pf = (t + 1 < nt);
    const size_t k1 = (size_t)(t + 1) << 6;

    asm volatile("s_waitcnt vmcnt(2)" ::: "memory");
    __builtin_amdgcn_s_barrier();
    __builtin_amdgcn_sched_barrier(0);

    bf16x8 bfr[4][2], af[4];
    // phase 0
    if (pf) {
      gl_lds16(W + (srcB[0] + k1), Bn + 0 * 4096 + wave * 512);
      gl_lds16(W + (srcB[1] + k1), Bn + 1 * 4096 + wave * 512);
    }
#pragma unroll
    for (int nf = 0; nf < 4; ++nf) {
      int rb = wn * 64 + nf * 16 + lrow;
      bfr[nf][0] = *(const bf16x8*)&Bb[rb * 64 + ((lquad ^ (rb & 7)) << 3)];
    }
#pragma unroll
    for (int j = 0; j < 4; ++j) {
      int ra = wm * 128 + j * 16 + lrow;
      af[j] = *(const bf16x8*)&Ab[ra * 64 + ((lquad ^ (ra & 7)) << 3)];
    }
    __builtin_amdgcn_s_setprio(1);
#pragma unroll
    for (int j = 0; j < 4; ++j)
#pragma unroll
      for (int nf = 0; nf < 4; ++nf)
        acc[j][nf] = __builtin_amdgcn_mfma_f32_16x16x32_bf16(af[j], bfr[nf][0], acc[j][nf], 0, 0, 0);
    __builtin_amdgcn_s_setprio(0);

    // phase 1
    if (pf) {
      gl_lds16(W + (srcB[2] + k1), Bn + 2 * 4096 + wave * 512);
      gl_lds16(W + (srcB[3] + k1), Bn + 3 * 4096 + wave * 512);
    }
#pragma unroll
    for (int nf = 0; nf < 4; ++nf) {
      int rb = wn * 64 + nf * 16 + lrow;
      bfr[nf][1] = *(const bf16x8*)&Bb[rb * 64 + (((4 + lquad) ^ (rb & 7)) << 3)];
    }
#pragma unroll
    for (int j = 0; j < 4; ++j) {
      int ra = wm * 128 + j * 16 + lrow;
      af[j] = *(const bf16x8*)&Ab[ra * 64 + (((4 + lquad) ^ (ra & 7)) << 3)];
    }
    __builtin_amdgcn_s_setprio(1);
#pragma unroll
    for (int j = 0; j < 4; ++j)
#pragma unroll
      for (int nf = 0; nf < 4; ++nf)
        acc[j][nf] = __builtin_amdgcn_mfma_f32_16x16x32_bf16(af[j], bfr[nf][1], acc[j][nf], 0, 0, 0);
    __builtin_amdgcn_s_setprio(0);

    // phase 2 entry
    if (pf) asm volatile("s_waitcnt vmcnt(4)" ::: "memory");
    else    asm volatile("s_waitcnt vmcnt(0)" ::: "memory");
    __builtin_amdgcn_s_barrier();
    __builtin_amdgcn_sched_barrier(0);

    // phase 2
    if (pf) {
      gl_lds16(A + (srcA[0] + k1), An + dstA[0]);
      gl_lds16(A + (srcA[1] + k1), An + dstA[1]);
    }
#pragma unroll
    for (int j = 0; j < 4; ++j) {
      int ra = wm * 128 + 64 + j * 16 + lrow;
      af[j] = *(const bf16x8*)&Ab[ra * 64 + ((lquad ^ (ra & 7)) << 3)];
    }
    __builtin_amdgcn_s_setprio(1);
#pragma unroll
    for (int j = 0; j < 4; ++j)
#pragma unroll
      for (int nf = 0; nf < 4; ++nf)
        acc[4 + j][nf] = __builtin_amdgcn_mfma_f32_16x16x32_bf16(af[j], bfr[nf][0], acc[4 + j][nf], 0, 0, 0);
    __builtin_amdgcn_s_setprio(0);

    // phase 3
    if (pf) {
      gl_lds16(A + (srcA[2] + k1), An + dstA[2]);
      gl_lds16(A + (srcA[3] + k1), An + dstA[3]);
    }
#pragma unroll
    for (int j = 0; j < 4; ++j) {
      int ra = wm * 128 + 64 + j * 16 + lrow;
      af[j] = *(const bf16x8*)&Ab[ra * 64 + (((4 + lquad) ^ (ra & 7)) << 3)];
    }
    __builtin_amdgcn_s_setprio(1);
#pragma unroll
    for (int j = 0; j < 4; ++j)
#pragma unroll
      for (int nf = 0; nf < 4; ++nf)
        acc[4 + j][nf] = __builtin_amdgcn_mfma_f32_16x16x32_bf16(af[j], bfr[nf][1], acc[4 + j][nf], 0, 0, 0);
    __builtin_amdgcn_s_setprio(0);
  }

#pragma unroll
  for (int mf = 0; mf < 8; ++mf) {
    int row = m0 + wm * 128 + mf * 16 + lquad * 4;
#pragma unroll
    for (int nf = 0; nf < 4; ++nf) {
      int col = n0 + wn * 64 + nf * 16 + lrow;
      float bv = bias ? bias[col] : 0.f;
#pragma unroll
      for (int r = 0; r < 4; ++r) {
        float val = acc[mf][nf][r] + bv;
        if (outb) outb[(size_t)(row + r) * N + col] = f2bf(val);
        else      outf[(size_t)(row + r) * N + col] = val;
      }
    }
  }
}

// ---------------- finalize: Q-rope + K (sum partials + bias + rope) + vT (sum partials) ----------------
__global__ __launch_bounds__(256) void finalize_kernel(
    u16* __restrict__ qkv, const float* __restrict__ cosb,
    const float* __restrict__ sinb, const float* __restrict__ part,
    const float* __restrict__ bias, u16* __restrict__ vT, int kparts) {
  int t = blockIdx.x * 256 + threadIdx.x;  // 2^22 total
  if (t < (1 << 21)) {
    int d = (t & 15) << 2;        // 0,4,...,60
    int hs = (t >> 4) & 31;
    int s = (t >> 9) & 2047;
    int b = t >> 20;
    size_t base = (size_t)(b * S_ + s) * QKVW_ + hs * HD_;
    float4 c0 = *(const float4*)&cosb[s * HD_ + d];
    float4 s0 = *(const float4*)&sinb[s * HD_ + d];
    float4 c1 = *(const float4*)&cosb[s * HD_ + 64 + d];
    float4 s1 = *(const float4*)&sinb[s * HD_ + 64 + d];
    float x1x, x1y, x1z, x1w, x2x, x2y, x2z, x2w, sc;
    if (hs < NH_) {
      ushort4 x1u = *(const ushort4*)&qkv[base + d];
      ushort4 x2u = *(const ushort4*)&qkv[base + 64 + d];
      sc = SCALING_;
      x1x = bf2f(x1u.x); x1y = bf2f(x1u.y); x1z = bf2f(x1u.z); x1w = bf2f(x1u.w);
      x2x = bf2f(x2u.x); x2y = bf2f(x2u.y); x2z = bf2f(x2u.z); x2w = bf2f(x2u.w);
    } else {
      int pc = (hs - 28) * 128;
      size_t prow = (size_t)(b * S_ + s) * 1024;
      float4 b1 = *(const float4*)&bias[3584 + pc + d];
      float4 b2 = *(const float4*)&bias[3584 + pc + 64 + d];
      x1x = b1.x; x1y = b1.y; x1z = b1.z; x1w = b1.w;
      x2x = b2.x; x2y = b2.y; x2z = b2.z; x2w = b2.w;
      for (int kc = 0; kc < kparts; ++kc) {
        const float* pb = part + (size_t)kc * 4194304;
        float4 p1 = *(const float4*)&pb[prow + pc + d];
        float4 p2 = *(const float4*)&pb[prow + pc + 64 + d];
        x1x += p1.x; x1y += p1.y; x1z += p1.z; x1w += p1.w;
        x2x += p2.x; x2y += p2.y; x2z += p2.z; x2w += p2.w;
      }
      sc = 1.f;
    }
    ushort4 y1u, y2u;
    y1u.x = f2bf((x1x * c0.x - x2x * s0.x) * sc);
    y1u.y = f2bf((x1y * c0.y - x2y * s0.y) * sc);
    y1u.z = f2bf((x1z * c0.z - x2z * s0.z) * sc);
    y1u.w = f2bf((x1w * c0.w - x2w * s0.w) * sc);
    y2u.x = f2bf((x2x * c1.x + x1x * s1.x) * sc);
    y2u.y = f2bf((x2y * c1.y + x1y * s1.y) * sc);
    y2u.z = f2bf((x2z * c1.z + x1z * s1.z) * sc);
    y2u.w = f2bf((x2w * c1.w + x1w * s1.w) * sc);
    *(ushort4*)&qkv[base + d] = y1u;
    *(ushort4*)&qkv[base + 64 + d] = y2u;
  } else {
    int t2 = t - (1 << 21);
    int s = t2 & 2047;
    int d = (t2 >> 11) & 127;
    int kvb = t2 >> 18;  // b*4+kv
    size_t off = (size_t)((kvb >> 2) * S_ + s) * 1024 + 512 + (kvb & 3) * 128 + d;
    float v = bias[4096 + (kvb & 3) * 128 + d];
    for (int kc = 0; kc < kparts; ++kc)
      v += part[(size_t)kc * 4194304 + off];
    vT[t2] = f2bf(v);
  }
}

// ---------------- fused RoPE + V-transpose (fallback path, reads qkv only) ----------------
__global__ __launch_bounds__(256) void rope_vtrans_kernel(
    u16* __restrict__ qkv, const float* __restrict__ cosb,
    const float* __restrict__ sinb, u16* __restrict__ vT) {
  int t = blockIdx.x * 256 + threadIdx.x;  // 2^22 total
  if (t < (1 << 21)) {
    int d = (t & 15) << 2;
    int hs = (t >> 4) & 31;
    int s = (t >> 9) & 2047;
    int b = t >> 20;
    size_t base = (size_t)(b * S_ + s) * QKVW_ + hs * HD_;
    float4 c0 = *(const float4*)&cosb[s * HD_ + d];
    float4 s0 = *(const float4*)&sinb[s * HD_ + d];
    float4 c1 = *(const float4*)&cosb[s * HD_ + 64 + d];
    float4 s1 = *(const float4*)&sinb[s * HD_ + 64 + d];
    ushort4 x1u = *(const ushort4*)&qkv[base + d];
    ushort4 x2u = *(const ushort4*)&qkv[base + 64 + d];
    float sc = (hs < NH_) ? SCALING_ : 1.f;
    float x1x = bf2f(x1u.x), x1y = bf2f(x1u.y), x1z = bf2f(x1u.z), x1w = bf2f(x1u.w);
    float x2x = bf2f(x2u.x), x2y = bf2f(x2u.y), x2z = bf2f(x2u.z), x2w = bf2f(x2u.w);
    ushort4 y1u, y2u;
    y1u.x = f2bf((x1x * c0.x - x2x * s0.x) * sc);
    y1u.y = f2bf((x1y * c0.y - x2y * s0.y) * sc);
    y1u.z = f2bf((x1z * c0.z - x2z * s0.z) * sc);
    y1u.w = f2bf((x1w * c0.w - x2w * s0.w) * sc);
    y2u.x = f2bf((x2x * c1.x + x1x * s1.x) * sc);
    y2u.y = f2bf((x2y * c1.y + x1y * s1.y) * sc);
    y2u.z = f2bf((x2z * c1.z + x1z * s1.z) * sc);
    y2u.w = f2bf((x2w * c1.w + x1w * s1.w) * sc);
    *(ushort4*)&qkv[base + d] = y1u;
    *(ushort4*)&qkv[base + 64 + d] = y2u;
  } else {
    t -= (1 << 21);
    int s = t & 2047;
    int d = (t >> 11) & 127;
    int kvb = t >> 18;
    vT[t] = qkv[(size_t)((kvb >> 2) * S_ + s) * QKVW_
                + (HID_ + NKV_ * HD_) + (kvb & 3) * HD_ + d];
  }
}

// ---------------- flash attention: 256 q-rows/block, 8 waves (R15) ----------------
// Per-wave structure identical to the verified 4-wave kernel (32 rows/wave,
// swapped-QK^T in-register softmax, dbuf K/V with one raw s_barrier + vmcnt(0)
// per tile, stage issued a full tile ahead). Doubling rows/block HALVES the
// staging traffic + barrier drains per q-row. LDS = Kdbuf 32K + Vdbuf 32K +
// P[256][64] 32K = 96KB -> 1 block/CU x 8 waves = same 8 waves/CU as before.
// grid (56, 8) qt desc (LPT), nkt = 4*qt+4, causal tail = last 4 tiles.
__global__ __launch_bounds__(512, 2)
void attn_kernel(const u16* __restrict__ qkv, const u16* __restrict__ vT,
                 u16* __restrict__ out) {
  __shared__ u16 smem[49152] __attribute__((aligned(16)));
  // [0] K buf0 | [8192] K buf1 | [16384] V buf0 | [24576] V buf1 | [32768] P 256x64
  u16* p_sm = smem + 32768;
  const int tid = threadIdx.x;
  const int wave = tid >> 6, lane = tid & 63;
  const int lrow = lane & 15, lquad = lane >> 4;
  const int qt = 7 - (int)blockIdx.y;  // LPT: heavy tiles dispatched first
  const int bh = blockIdx.x;
  const int b = bh / NH_, h = bh % NH_, kv = h / NREP_;

  const u16* kbase = qkv + (size_t)(b * S_) * QKVW_ + HID_ + kv * HD_;
  const u16* vbase = vT + (size_t)(b * NKV_ + kv) * HD_ * S_;

  // stage one 64-key tile with 512 threads: K [64][128] + vT [128][64], swizzled
  auto stage = [&](int k0, u16* k_d, u16* v_d) {
#pragma unroll
    for (int is = 0; is < 2; ++is) {
      int kr = is * 32 + (tid >> 4);
      int kcs = (((tid & 15) ^ (kr & 7)) << 3);
      gl_lds16(kbase + (size_t)(k0 + kr) * QKVW_ + kcs, k_d + is * 4096 + wave * 512);
      int vr = is * 64 + (tid >> 3);
      int vcs = (((tid & 7) ^ (vr & 7)) << 3);
      gl_lds16(vbase + (size_t)vr * S_ + k0 + vcs, v_d + is * 4096 + wave * 512);
    }
  };

  stage(0, smem, smem + 16384);

  bf16x8 aq[2][4];
  {
    const u16* qrow = qkv + (size_t)(b * S_ + qt * 256 + wave * 32) * QKVW_ + h * HD_;
#pragma unroll
    for (int rg = 0; rg < 2; ++rg)
#pragma unroll
      for (int ks = 0; ks < 4; ++ks)
        aq[rg][ks] = *(const bf16x8*)(qrow + (size_t)(rg * 16 + lrow) * QKVW_ + ks * 32 + lquad * 8);
  }

  f32x4 oacc[2][8] = {};
  float m_run[2], l_run[2];
#pragma unroll
  for (int rg = 0; rg < 2; ++rg) { m_run[rg] = -1e30f; l_run[rg] = 0.f; }

  const int nkt = 4 * qt + 4;
  for (int kt = 0; kt < nkt; ++kt) {
    const int cur = kt & 1;
    u16* k_c = smem + cur * 8192;
    u16* v_c = smem + 16384 + cur * 8192;
    const int k0 = kt * 64;

    asm volatile("s_waitcnt vmcnt(0)" ::: "memory");
    __builtin_amdgcn_s_barrier();
    __builtin_amdgcn_sched_barrier(0);
    if (kt + 1 < nkt)
      stage(k0 + 64, smem + (cur ^ 1) * 8192, smem + 16384 + (cur ^ 1) * 8192);

    // S^T = K Q^T via swapped mfma: sa[rg][cg][r] = S[q = lane&15 + 16rg]
    //                                               [key = cg*16 + lquad*4 + r]
    f32x4 sa[2][4] = {};
#pragma unroll
    for (int ks = 0; ks < 4; ++ks) {
      bf16x8 kb[4];
#pragma unroll
      for (int cg = 0; cg < 4; ++cg) {
        int row = cg * 16 + lrow;
        int g = (ks * 4 + lquad) ^ (row & 7);
        kb[cg] = *(const bf16x8*)&k_c[row * 128 + g * 8];
      }
      __builtin_amdgcn_s_setprio(1);
#pragma unroll
      for (int rg = 0; rg < 2; ++rg)
#pragma unroll
        for (int cg = 0; cg < 4; ++cg)
          sa[rg][cg] = __builtin_amdgcn_mfma_f32_16x16x32_bf16(kb[cg], aq[rg][ks], sa[rg][cg], 0, 0, 0);
      __builtin_amdgcn_s_setprio(0);
    }

    // causal mask: only the last 4 tiles (keys >= qt*256) can have masked entries
    if (kt >= 4 * qt) {
#pragma unroll
      for (int rg = 0; rg < 2; ++rg) {
        int qg = qt * 256 + wave * 32 + rg * 16 + lrow;
#pragma unroll
        for (int cg = 0; cg < 4; ++cg) {
          int kg = k0 + cg * 16 + lquad * 4;
#pragma unroll
          for (int r = 0; r < 4; ++r)
            if (kg + r > qg) sa[rg][cg][r] -= 1e9f;
        }
      }
    }

    // in-register online softmax (row = lane-local)
    float mt[2];
#pragma unroll
    for (int rg = 0; rg < 2; ++rg) {
      float mv = fmaxf(fmaxf(sa[rg][0][0], sa[rg][0][1]), fmaxf(sa[rg][0][2], sa[rg][0][3]));
#pragma unroll
      for (int cg = 1; cg < 4; ++cg) {
        mv = fmaxf(mv, fmaxf(fmaxf(sa[rg][cg][0], sa[rg][cg][1]),
                             fmaxf(sa[rg][cg][2], sa[rg][cg][3])));
      }
      mv = fmaxf(mv, __shfl_xor(mv, 16));
      mv = fmaxf(mv, __shfl_xor(mv, 32));
      mt[rg] = mv;
    }
    float need = fmaxf(mt[0] - m_run[0], mt[1] - m_run[1]);
    if (!__all(need <= 8.0f)) {  // wave-uniform rescale (defer-max, T13)
      float al[2];
#pragma unroll
      for (int rg = 0; rg < 2; ++rg) {
        float mn = fmaxf(m_run[rg], mt[rg]);
        al[rg] = __expf(m_run[rg] - mn);
        m_run[rg] = mn;
        l_run[rg] *= al[rg];
      }
#pragma unroll
      for (int rg = 0; rg < 2; ++rg)
#pragma unroll
        for (int r = 0; r < 4; ++r) {
          float alr = __shfl(al[rg], lquad * 4 + r, 16);
#pragma unroll
          for (int dg = 0; dg < 8; ++dg) oacc[rg][dg][r] *= alr;
        }
    }
    // exp, row-sum, pack to bf16, write P (8x ds_write_b64)
#pragma unroll
    for (int rg = 0; rg < 2; ++rg) {
      float rs = 0.f;
      uint2 pk[4];
#pragma unroll
      for (int cg = 0; cg < 4; ++cg) {
        float p0 = __expf(sa[rg][cg][0] - m_run[rg]);
        float p1 = __expf(sa[rg][cg][1] - m_run[rg]);
        float p2 = __expf(sa[rg][cg][2] - m_run[rg]);
        float p3 = __expf(sa[rg][cg][3] - m_run[rg]);
        rs += (p0 + p1) + (p2 + p3);
        pk[cg].x = cvtpk_bf16(p0, p1);
        pk[cg].y = cvtpk_bf16(p2, p3);
      }
      rs += __shfl_xor(rs, 16);
      rs += __shfl_xor(rs, 32);
      l_run[rg] += rs;
      int q = wave * 32 + rg * 16 + lrow;
#pragma unroll
      for (int cg = 0; cg < 4; ++cg) {
        int g = (cg * 2 + (lquad >> 1)) ^ (q & 7);
        *(uint2*)&p_sm[q * 64 + g * 8 + (lquad & 1) * 4] = pk[cg];
      }
    }

    // O += P V (same-wave RAW through LDS)
#pragma unroll
    for (int ks2 = 0; ks2 < 2; ++ks2) {
      bf16x8 pa[2];
#pragma unroll
      for (int rg = 0; rg < 2; ++rg) {
        int q = wave * 32 + rg * 16 + lrow;
        int g = (ks2 * 4 + lquad) ^ (q & 7);
        pa[rg] = *(const bf16x8*)&p_sm[q * 64 + g * 8];
      }
      __builtin_amdgcn_s_setprio(1);
#pragma unroll
      for (int dg = 0; dg < 8; ++dg) {
        int row = dg * 16 + lrow;
        int g = (ks2 * 4 + lquad) ^ (row & 7);
        bf16x8 vb = *(const bf16x8*)&v_c[row * 64 + g * 8];
#pragma unroll
        for (int rg = 0; rg < 2; ++rg)
          oacc[rg][dg] = __builtin_amdgcn_mfma_f32_16x16x32_bf16(pa[rg], vb, oacc[rg][dg], 0, 0, 0);
      }
      __builtin_amdgcn_s_setprio(0);
    }
  }

  // epilogue: out[b, s, h*128 + d] bf16
#pragma unroll
  for (int rg = 0; rg < 2; ++rg) {
    float linv = 1.f / l_run[rg];
#pragma unroll
    for (int r = 0; r < 4; ++r) {
      float inv = __shfl(linv, lquad * 4 + r, 16);
      int qg = qt * 256 + wave * 32 + rg * 16 + lquad * 4 + r;
      u16* ob = out + (size_t)(b * S_ + qg) * HID_ + h * HD_;
#pragma unroll
      for (int dg = 0; dg < 8; ++dg)
        ob[dg * 16 + lrow] = f2bf(oacc[rg][dg][r] * inv);
    }
  }
}

// ---------------- launch ----------------
extern "C" void kernel_launch(void* const* d_in, const int* in_sizes, int n_in,
                              void* d_out, int out_size, void* d_ws, size_t ws_size,
                              hipStream_t stream) {
  const float* hid  = (const float*)d_in[0];
  const float* cosb = (const float*)d_in[1];
  const float* sinb = (const float*)d_in[2];
  // d_in[3] attention_mask: deterministic causal -1e9, applied structurally
  const float* q_w = (const float*)d_in[4];
  const float* q_b = (const float*)d_in[5];
  const float* k_w = (const float*)d_in[6];
  const float* k_b = (const float*)d_in[7];
  const float* v_w = (const float*)d_in[8];
  const float* v_b = (const float*)d_in[9];
  const float* o_w = (const float*)d_in[10];
  float* out = (float*)d_out;

  constexpr size_t OFF_HID  = 0;                       // 4096*3584 bf16 (later attn out)
  constexpr size_t OFF_W    = 29360128;                // 4608*3584 bf16
  constexpr size_t OFF_OW   = OFF_W + 33030144;        // 3584*3584 bf16
  constexpr size_t OFF_QKV  = OFF_OW + 25690112;       // 4096*4608 bf16
  constexpr size_t OFF_VT   = OFF_QKV + 37748736;      // 2*4*128*2048 bf16
  constexpr size_t OFF_BIAS = OFF_VT + 4194304;        // 4608 f32
  constexpr size_t OFF_PART = OFF_BIAS + 18432;        // KV partials
  constexpr size_t WS_HYB4  = OFF_PART + 4ull * 16777216;  // ~197 MB (4 buffers)
  constexpr size_t WS_HYB   = OFF_PART + 16777216;     // ~147 MB (1 buffer, atomic)
  constexpr size_t WS_NEED  = OFF_PART;                // ~130 MB (R9 path)
  constexpr size_t WS_OLD   = OFF_W + 33030144 + 37748736 + 4194304 + 18432;

  char* ws = (char*)d_ws;
  if (ws_size >= WS_HYB4) {
    u16*  hid_b = (u16*)(ws + OFF_HID);
    u16*  w_b   = (u16*)(ws + OFF_W);
    u16*  ow_b  = (u16*)(ws + OFF_OW);
    u16*  qkv   = (u16*)(ws + OFF_QKV);
    u16*  vT    = (u16*)(ws + OFF_VT);
    float* bias = (float*)(ws + OFF_BIAS);
    float* part = (float*)(ws + OFF_PART);
    // 1. casts + bias (no zeroing needed — plain-store partials)
    megacast_kernel<<<43026, 256, 0, stream>>>(
        (const float4*)hid, (const float4*)q_w, (const float4*)k_w,
        (const float4*)v_w, (const float4*)o_w,
        (ushort4*)hid_b, (ushort4*)w_b, (ushort4*)ow_b,
        q_b, k_b, v_b, bias, nullptr);
    // 2. QKV hybrid (Q LPT-first; KV split-K=4, plain stores into 4 buffers)
    qkv_hybrid_kernel<<<480, 512, 0, stream>>>(hid_b, w_b, bias, qkv, part, 4);
    // 3. finalize: Q-rope + K(sum 4 + bias + rope) + vT(sum 4 + bias)
    finalize_kernel<<<16384, 256, 0, stream>>>(qkv, cosb, sinb, part, bias, vT, 4);
    // 4. flash attention (256 q-rows/block, 8 waves)
    attn_kernel<<<dim3(B_ * NH_, 8), 512, 0, stream>>>(qkv, vT, hid_b);
    // 5. output projection
    gemm256_kernel<<<(M_ / 256) * (HID_ / 256), 512, 0, stream>>>(
        hid_b, ow_b, nullptr, nullptr, out, M_, HID_, HID_);
  } else if (ws_size >= WS_HYB) {
    // single zeroed buffer + atomics
    u16*  hid_b = (u16*)(ws + OFF_HID);
    u16*  w_b   = (u16*)(ws + OFF_W);
    u16*  ow_b  = (u16*)(ws + OFF_OW);
    u16*  qkv   = (u16*)(ws + OFF_QKV);
    u16*  vT    = (u16*)(ws + OFF_VT);
    float* bias = (float*)(ws + OFF_BIAS);
    float* part = (float*)(ws + OFF_PART);
    megacast_kernel<<<47122, 256, 0, stream>>>(
        (const float4*)hid, (const float4*)q_w, (const float4*)k_w,
        (const float4*)v_w, (const float4*)o_w,
        (ushort4*)hid_b, (ushort4*)w_b, (ushort4*)ow_b,
        q_b, k_b, v_b, bias, (float4*)part);
    qkv_hybrid_kernel<<<480, 512, 0, stream>>>(hid_b, w_b, bias, qkv, part, 1);
    finalize_kernel<<<16384, 256, 0, stream>>>(qkv, cosb, sinb, part, bias, vT, 1);
    attn_kernel<<<dim3(B_ * NH_, 8), 512, 0, stream>>>(qkv, vT, hid_b);
    gemm256_kernel<<<(M_ / 256) * (HID_ / 256), 512, 0, stream>>>(
        hid_b, ow_b, nullptr, nullptr, out, M_, HID_, HID_);
  } else if (ws_size >= WS_NEED) {
    // R9 path
    u16*  hid_b = (u16*)(ws + OFF_HID);
    u16*  w_b   = (u16*)(ws + OFF_W);
    u16*  ow_b  = (u16*)(ws + OFF_OW);
    u16*  qkv   = (u16*)(ws + OFF_QKV);
    u16*  vT    = (u16*)(ws + OFF_VT);
    float* bias = (float*)(ws + OFF_BIAS);
    megacast_kernel<<<43026, 256, 0, stream>>>(
        (const float4*)hid, (const float4*)q_w, (const float4*)k_w,
        (const float4*)v_w, (const float4*)o_w,
        (ushort4*)hid_b, (ushort4*)w_b, (ushort4*)ow_b,
        q_b, k_b, v_b, bias, nullptr);
    gemm_bt_kernel<<<(M_ / 128) * (QKVW_ / 128), 256, 0, stream>>>(
        hid_b, w_b, bias, qkv, nullptr, M_, QKVW_, HID_);
    rope_vtrans_kernel<<<16384, 256, 0, stream>>>(qkv, cosb, sinb, vT);
    attn_kernel<<<dim3(B_ * NH_, 8), 512, 0, stream>>>(qkv, vT, hid_b);
    gemm256_kernel<<<(M_ / 256) * (HID_ / 256), 512, 0, stream>>>(
        hid_b, ow_b, nullptr, nullptr, out, M_, HID_, HID_);
  } else if (ws_size >= WS_OLD) {
    // old 104.4 MB layout, o_w reuses w_b
    u16*  hid_b = (u16*)(ws + OFF_HID);
    u16*  w_b   = (u16*)(ws + OFF_W);
    u16*  qkv   = (u16*)(ws + OFF_W + 33030144);
    u16*  vT    = (u16*)(ws + OFF_W + 33030144 + 37748736);
    float* bias = (float*)(ws + OFF_W + 33030144 + 37748736 + 4194304);
    f2b4_kernel<<<14336, 256, 0, stream>>>((const float4*)hid, (ushort4*)hid_b, 3670016);
    f2b4_kernel<<<12544, 256, 0, stream>>>((const float4*)q_w, (ushort4*)w_b, 3211264);
    f2b4_kernel<<<1792, 256, 0, stream>>>((const float4*)k_w, (ushort4*)(w_b + 12845056), 458752);
    f2b4_kernel<<<1792, 256, 0, stream>>>((const float4*)v_w, (ushort4*)(w_b + 14680064), 458752);
    bias_cat_kernel<<<18, 256, 0, stream>>>(q_b, k_b, v_b, bias);
    gemm_bt_kernel<<<(M_ / 128) * (QKVW_ / 128), 256, 0, stream>>>(
        hid_b, w_b, bias, qkv, nullptr, M_, QKVW_, HID_);
    f2b4_kernel<<<12544, 256, 0, stream>>>((const float4*)o_w, (ushort4*)w_b, 3211264);
    rope_vtrans_kernel<<<16384, 256, 0, stream>>>(qkv, cosb, sinb, vT);
    attn_kernel<<<dim3(B_ * NH_, 8), 512, 0, stream>>>(qkv, vT, hid_b);
    gemm256_kernel<<<(M_ / 256) * (HID_ / 256), 512, 0, stream>>>(
        hid_b, w_b, nullptr, nullptr, out, M_, HID_, HID_);
  }
  // else: fail loudly via absmax
}